// Round 5
// baseline (10763.733 us; speedup 1.0000x reference)
//
#include <hip/hip_runtime.h>
#include <hip/hip_bf16.h>
#include <cmath>

// ---------------------------------------------------------------------------
// VQ-VAE forward, round 5.
// Round-4 diagnosis: ws_size is small (~16MB) => per-sample scratch of 9MB
// forced chunk=1 => every dispatch ran 128-256 blocks (1 block/CU) x 450
// launches: latency-starved regardless of kernel quality.
// This round: per-sample scratch 5MB (C 2MB + D 1MB + B 2MB):
//   - enc_c1 fused into enc_c2 (A never materialized; recomputed in LDS)
//   - dec_c2 output stored bf16 overlaid on dead C slot (decoder tail only;
//     VQ path stays fp32 end-to-end to protect perplexity)
//   - vq writes q into dead D slot, then d2d-copied to qn output
// Chunk = clamp(avail/5MB, 1, 32); all grids scale with chunk.
// ---------------------------------------------------------------------------

static constexpr int NPOS  = 131072;        // 32*64*64 positions at VQ
static constexpr long long NELEM = 8388608; // NPOS * 64

// ======== fused enc_c1 (4x4 s2 p1) + enc_c2 (4x4 s2 p1): x -> B ============
// x: (b,1,256,256). w1:(64,1,4,4) b1:(64). w2:(128,64,4,4) b2:(128).
// out: (b,128,64,64), relu applied after both convs.
// Block: 4 out rows x 64 cols, OCB=16. grid (16, 8, cur), 256 threads.
__global__ void __launch_bounds__(256) enc12_t(
    const float* __restrict__ x, const float* __restrict__ w1,
    const float* __restrict__ b1, const float* __restrict__ w2,
    const float* __restrict__ b2, float* __restrict__ out)
{
  __shared__ float xt[22 * 264];        // x rows 4ty-3..4ty+18, cols -3..258
  __shared__ float at[2][4][10 * 132];  // A rows 2ty-1..2ty+8, cols -1..128
  int tid = threadIdx.x;
  int r = tid >> 6, c = tid & 63;
  int ty  = blockIdx.x * 4;
  int oc0 = blockIdx.y * 16;
  int b   = blockIdx.z;
  const float* xb = x + (size_t)b * 65536;

  // stage x tile once (zero-padded)
  for (int idx = tid; idx < 22 * 262; idx += 256) {
    int rr = idx / 262, cc = idx - rr * 262;
    int gy = 4 * ty - 3 + rr, gx = cc - 3;
    float v = 0.f;
    if (gy >= 0 && gy < 256 && gx >= 0 && gx < 256) v = xb[gy * 256 + gx];
    xt[rr * 264 + cc] = v;
  }
  __syncthreads();

  float acc[16];
  #pragma unroll
  for (int o = 0; o < 16; ++o) acc[o] = b2[oc0 + o];

  for (int acb = 0; acb < 16; ++acb) {      // A channels, 4 per barrier
    float (*abuf)[10 * 132] = at[acb & 1];
    #pragma unroll
    for (int ii = 0; ii < 4; ++ii) {
      int ac = acb * 4 + ii;
      float bias1 = b1[ac];
      const float* wp = w1 + ac * 16;
      for (int idx = tid; idx < 1300; idx += 256) {
        int ar = idx / 130, acol = idx - ar * 130;
        int gar = 2 * ty - 1 + ar;            // global A row
        int gac = acol - 1;                   // global A col
        float v = 0.f;
        if (gar >= 0 && gar < 128 && gac >= 0 && gac < 128) {
          float s = bias1;
          // x local row = 2*ar+ky, local col = 2*acol+kx (see derivation)
          #pragma unroll
          for (int ky = 0; ky < 4; ++ky)
            #pragma unroll
            for (int kx = 0; kx < 4; ++kx)
              s += xt[(2 * ar + ky) * 264 + 2 * acol + kx] * wp[ky * 4 + kx];
          v = fmaxf(s, 0.f);
        }
        abuf[ii][ar * 132 + acol] = v;
      }
    }
    __syncthreads();

    #pragma unroll
    for (int ii = 0; ii < 4; ++ii) {
      int ac = acb * 4 + ii;
      float v[16];
      #pragma unroll
      for (int ky = 0; ky < 4; ++ky)
        #pragma unroll
        for (int kx = 0; kx < 4; ++kx)
          v[ky * 4 + kx] = abuf[ii][(2 * r + ky) * 132 + 2 * c + kx];
      #pragma unroll
      for (int t = 0; t < 16; ++t)
        #pragma unroll
        for (int o = 0; o < 16; ++o)
          acc[o] += v[t] * w2[((size_t)(oc0 + o) * 64 + ac) * 16 + t];
    }
  }

  float* ob = out + ((size_t)b * 128 + oc0) * 4096 + (ty + r) * 64 + c;
  #pragma unroll
  for (int o = 0; o < 16; ++o)
    ob[(size_t)o * 4096] = fmaxf(acc[o], 0.f);
}

// ======== 3x3 s1 p1 conv at 64x64 ==========================================
// TR rows x 64 cols per block (TR*64 threads), OCB out-ch, ICB=8 per barrier.
// WMODE 0: w (OC,IC,3,3).  WMODE 1 (transposed): w (IC,OC,3,3), flipped.
template<int IC, int OC, int TR, int OCB, int WMODE, bool BIAS, bool RELU_IN, bool RELU_OUT>
__global__ void __launch_bounds__(TR * 64) conv3_t(
    const float* __restrict__ in, const float* __restrict__ w,
    const float* __restrict__ bias, float* __restrict__ out)
{
  constexpr int ICB = 8;
  constexpr int NE = (TR + 2) * 66;
  __shared__ float lds[2][ICB][NE];
  int tid = threadIdx.x;
  int r = tid >> 6, c = tid & 63;
  int ty  = blockIdx.x * TR;
  int oc0 = blockIdx.y * OCB;
  int b   = blockIdx.z;

  const float* inb = in + (size_t)b * IC * 4096;
  float acc[OCB];
  #pragma unroll
  for (int o = 0; o < OCB; ++o) acc[o] = BIAS ? bias[oc0 + o] : 0.f;

  for (int icb = 0; icb < IC / ICB; ++icb) {
    float (*buf)[NE] = lds[icb & 1];
    #pragma unroll
    for (int ii = 0; ii < ICB; ++ii) {
      const float* pl = inb + (size_t)(icb * ICB + ii) * 4096;
      for (int idx = tid; idx < NE; idx += TR * 64) {
        int rr = idx / 66, cc = idx - rr * 66;
        int iy = ty + rr - 1, ix = cc - 1;
        float v = 0.f;
        if (iy >= 0 && iy < 64 && ix >= 0 && ix < 64) {
          v = pl[iy * 64 + ix];
          if (RELU_IN) v = fmaxf(v, 0.f);
        }
        buf[ii][idx] = v;
      }
    }
    __syncthreads();

    #pragma unroll
    for (int ii = 0; ii < ICB; ++ii) {
      int ic = icb * ICB + ii;
      float v[9];
      #pragma unroll
      for (int ky = 0; ky < 3; ++ky)
        #pragma unroll
        for (int kx = 0; kx < 3; ++kx)
          v[ky * 3 + kx] = buf[ii][(r + ky) * 66 + c + kx];

      #pragma unroll
      for (int t = 0; t < 9; ++t) {
        int ky = t / 3, kx = t - ky * 3;
        #pragma unroll
        for (int o = 0; o < OCB; ++o) {
          float wt = (WMODE == 0)
            ? w[((size_t)(oc0 + o) * IC + ic) * 9 + t]
            : w[((size_t)ic * OC + (oc0 + o)) * 9 + (2 - ky) * 3 + (2 - kx)];
          acc[o] += v[t] * wt;
        }
      }
    }
  }

  float* ob = out + ((size_t)b * OC + oc0) * 4096 + (ty + r) * 64 + c;
  #pragma unroll
  for (int o = 0; o < OCB; ++o) {
    float a = acc[o];
    if (RELU_OUT) a = fmaxf(a, 0.f);
    ob[(size_t)o * 4096] = a;
  }
}

// ======== res tail: out = relu(x) + w2 @ h (1x1), OCB=8 ====================
__global__ void __launch_bounds__(256) res_add_k(
    const float* __restrict__ x, const float* __restrict__ h,
    const float* __restrict__ w2, float* __restrict__ out)
{
  int p   = blockIdx.x * 256 + threadIdx.x;
  int oc0 = blockIdx.y * 8;
  int b   = blockIdx.z;
  const float* xb = x + ((size_t)b * 128 + oc0) * 4096 + p;
  float acc[8];
  #pragma unroll
  for (int o = 0; o < 8; ++o) acc[o] = fmaxf(xb[(size_t)o * 4096], 0.f);
  const float* hb = h + (size_t)b * 64 * 4096 + p;
  #pragma unroll 4
  for (int ic = 0; ic < 64; ++ic) {
    float v = hb[(size_t)ic * 4096];
    #pragma unroll
    for (int o = 0; o < 8; ++o)
      acc[o] += w2[(oc0 + o) * 64 + ic] * v;
  }
  float* ob = out + ((size_t)b * 128 + oc0) * 4096 + p;
  #pragma unroll
  for (int o = 0; o < 8; ++o) ob[(size_t)o * 4096] = acc[o];
}

// ======== dec_c2 as 4 parity convs: (b,128,64,64) -> bf16 (b,64,128,128) ===
__global__ void __launch_bounds__(256) dec2p_t(
    const float* __restrict__ in, const float* __restrict__ w,
    const float* __restrict__ bias, __hip_bfloat16* __restrict__ out)
{
  constexpr int IC = 128, OC = 64, OCB = 16, ICB = 8;
  __shared__ float lds[2][ICB][330];   // 5 rows x 66 cols
  int tid = threadIdx.x;
  int r = tid >> 6, c = tid & 63;      // 4 y-rows x 64 x-cols (input grid)
  int pg = blockIdx.y & 3;
  int ry = pg & 1, rx = pg >> 1;
  int oc0 = (blockIdx.y >> 2) * OCB;
  int y0 = blockIdx.x * 4;
  int b  = blockIdx.z;

  int kyA = 1 - ry, kyB = 3 - ry, kxA = 1 - rx, kxB = 3 - rx;
  int ybase = y0 - 1 + ry, xbase = rx - 1;

  const float* inb = in + (size_t)b * IC * 4096;
  float acc[OCB];
  #pragma unroll
  for (int o = 0; o < OCB; ++o) acc[o] = bias[oc0 + o];

  for (int icb = 0; icb < IC / ICB; ++icb) {
    float (*buf)[330] = lds[icb & 1];
    #pragma unroll
    for (int ii = 0; ii < ICB; ++ii) {
      const float* pl = inb + (size_t)(icb * ICB + ii) * 4096;
      for (int idx = tid; idx < 330; idx += 256) {
        int rr = idx / 66, cc = idx - rr * 66;
        int iy = ybase + rr, ix = xbase + cc;
        float v = 0.f;
        if (iy >= 0 && iy < 64 && ix >= 0 && ix < 64)
          v = fmaxf(pl[iy * 64 + ix], 0.f);
        buf[ii][idx] = v;
      }
    }
    __syncthreads();

    #pragma unroll
    for (int ii = 0; ii < ICB; ++ii) {
      int ic = icb * ICB + ii;
      float vpp = buf[ii][(r + 1) * 66 + c + 1];
      float vp0 = buf[ii][(r + 1) * 66 + c];
      float v0p = buf[ii][r * 66 + c + 1];
      float v00 = buf[ii][r * 66 + c];
      const float* wp = w + (size_t)ic * OC * 16;
      #pragma unroll
      for (int o = 0; o < OCB; ++o) {
        const float* wo = wp + (size_t)(oc0 + o) * 16;
        acc[o] += vpp * wo[kyA * 4 + kxA] + vp0 * wo[kyA * 4 + kxB]
                + v0p * wo[kyB * 4 + kxA] + v00 * wo[kyB * 4 + kxB];
      }
    }
  }

  __hip_bfloat16* ob = out + ((size_t)b * OC + oc0) * 16384;
  int oy = 2 * (y0 + r) + ry, ox0 = rx;
  #pragma unroll
  for (int o = 0; o < OCB; ++o)
    ob[(size_t)o * 16384 + oy * 128 + 2 * c + ox0] =
        __float2bfloat16(fmaxf(acc[o], 0.f));
}

// ======== dec_c3: transposed 4x4 s2 p1, bf16 (b,64,128,128) -> (b,1,256,256)
__global__ void __launch_bounds__(256) dec3_t(
    const __hip_bfloat16* __restrict__ in, const float* __restrict__ w,
    const float* __restrict__ bias, float* __restrict__ out)
{
  constexpr int ICB = 4;
  __shared__ float lds[2][ICB][520];   // 4 rows x 130 cols
  int tid = threadIdx.x;
  int yr = tid >> 7, x = tid & 127;
  int y0 = blockIdx.x * 2;
  int y  = y0 + yr;
  int b  = blockIdx.z;

  const int kt[2][2] = {{1, 3}, {0, 2}};
  const int dt[2][2] = {{1, 0}, {2, 1}};

  const __hip_bfloat16* inb = in + (size_t)b * 64 * 16384;
  float acc[4] = {0.f, 0.f, 0.f, 0.f};

  for (int icb = 0; icb < 64 / ICB; ++icb) {
    float (*buf)[520] = lds[icb & 1];
    #pragma unroll
    for (int ii = 0; ii < ICB; ++ii) {
      const __hip_bfloat16* pl = inb + (size_t)(icb * ICB + ii) * 16384;
      for (int idx = tid; idx < 520; idx += 256) {
        int r2 = idx / 130, c2 = idx - r2 * 130;
        int iy = y0 + r2 - 1, ix = c2 - 1;
        float v = 0.f;
        if (iy >= 0 && iy < 128 && ix >= 0 && ix < 128)
          v = __bfloat162float(pl[iy * 128 + ix]);
        buf[ii][idx] = v;
      }
    }
    __syncthreads();

    #pragma unroll
    for (int ii = 0; ii < ICB; ++ii) {
      int ic = icb * ICB + ii;
      float v[9];
      #pragma unroll
      for (int dy = 0; dy < 3; ++dy)
        #pragma unroll
        for (int dx = 0; dx < 3; ++dx)
          v[dy * 3 + dx] = buf[ii][(yr + dy) * 130 + x + dx];
      const float* wp = w + (size_t)ic * 16;
      #pragma unroll
      for (int ry = 0; ry < 2; ++ry)
        #pragma unroll
        for (int rx = 0; rx < 2; ++rx)
          #pragma unroll
          for (int a = 0; a < 2; ++a)
            #pragma unroll
            for (int c2 = 0; c2 < 2; ++c2)
              acc[ry * 2 + rx] += v[dt[ry][a] * 3 + dt[rx][c2]]
                                * wp[kt[ry][a] * 4 + kt[rx][c2]];
    }
  }

  float b0 = bias[0];
  float* ob = out + (size_t)b * 65536;
  #pragma unroll
  for (int ry = 0; ry < 2; ++ry)
    #pragma unroll
    for (int rx = 0; rx < 2; ++rx)
      ob[(2 * y + ry) * 256 + 2 * x + rx] = tanhf(acc[ry * 2 + rx] + b0);
}

// ======== fused pre-VQ 1x1 conv + VQ (writes q into bounce buffer) =========
__global__ void __launch_bounds__(256) vq_k(
    const float* __restrict__ xres, const float* __restrict__ vw,
    const float* __restrict__ vb, const float* __restrict__ emb,
    float* __restrict__ qn, float* __restrict__ sum_sq, int* __restrict__ hist)
{
  int tid = threadIdx.x;
  int n = blockIdx.x * 256 + tid;
  int b = n >> 12;
  int pos = n & 4095;

  float z[64];
  #pragma unroll
  for (int k = 0; k < 64; ++k) z[k] = vb[k];

  const float* xb = xres + (size_t)b * 128 * 4096 + pos;
  for (int c = 0; c < 128; ++c) {
    float v = fmaxf(xb[(size_t)c * 4096], 0.f);
    #pragma unroll
    for (int k = 0; k < 64; ++k) z[k] += v * vw[k * 128 + c];
  }

  float z2 = 0.f;
  #pragma unroll
  for (int d = 0; d < 64; ++d) z2 += z[d] * z[d];

  float best = INFINITY;
  int bidx = 0;
  for (int k = 0; k < 64; ++k) {
    float dot = 0.f, e2 = 0.f;
    #pragma unroll
    for (int d = 0; d < 64; ++d) {
      float e = emb[k * 64 + d];
      dot += z[d] * e;
      e2  += e * e;
    }
    float dist = z2 + e2 - 2.f * dot;
    if (dist < best) { best = dist; bidx = k; }
  }

  float sq = 0.f;
  const float* eb = emb + bidx * 64;
  float* qb = qn + (size_t)b * 64 * 4096 + pos;
  #pragma unroll
  for (int d = 0; d < 64; ++d) {
    float e = eb[d];
    float df = e - z[d];
    sq += df * df;
    qb[(size_t)d * 4096] = e;
  }

  __shared__ float red[256];
  __shared__ int lh[64];
  red[tid] = sq;
  if (tid < 64) lh[tid] = 0;
  __syncthreads();
  atomicAdd(&lh[bidx], 1);
  for (int s = 128; s > 0; s >>= 1) {
    if (tid < s) red[tid] += red[tid + s];
    __syncthreads();
  }
  if (tid == 0) atomicAdd(sum_sq, red[0]);
  if (tid < 64) atomicAdd(&hist[tid], lh[tid]);
}

// ======== scratch init + scalar finalize ===================================
__global__ void init_k(float* sum_sq, int* hist)
{
  int t = threadIdx.x;
  if (t == 0) sum_sq[0] = 0.f;
  if (t < 64) hist[t] = 0;
}

__global__ void finalize_k(const float* __restrict__ sum_sq, const int* __restrict__ hist,
                           float* __restrict__ loss_out, float* __restrict__ perp_out)
{
  if (threadIdx.x == 0) {
    float mse = sum_sq[0] / (float)NELEM;
    loss_out[0] = 1.25f * mse;
    float ent = 0.f;
    for (int k = 0; k < 64; ++k) {
      float p = (float)hist[k] / (float)NPOS;
      ent += p * logf(p + 1e-10f);
    }
    perp_out[0] = expf(-ent);
  }
}

// ---------------------------------------------------------------------------
extern "C" void kernel_launch(void* const* d_in, const int* in_sizes, int n_in,
                              void* d_out, int out_size, void* d_ws, size_t ws_size,
                              hipStream_t stream)
{
  const float* x        = (const float*)d_in[0];
  const float* enc_c1_w = (const float*)d_in[1];
  const float* enc_c1_b = (const float*)d_in[2];
  const float* enc_c2_w = (const float*)d_in[3];
  const float* enc_c2_b = (const float*)d_in[4];
  const float* enc_c3_w = (const float*)d_in[5];
  const float* enc_c3_b = (const float*)d_in[6];
  const float* enc_r1_w = (const float*)d_in[7];
  const float* enc_r2_w = (const float*)d_in[8];
  const float* vqc_w    = (const float*)d_in[9];
  const float* vqc_b    = (const float*)d_in[10];
  const float* emb      = (const float*)d_in[11];
  const float* dec_c1_w = (const float*)d_in[12];
  const float* dec_c1_b = (const float*)d_in[13];
  const float* dec_r1_w = (const float*)d_in[14];
  const float* dec_r2_w = (const float*)d_in[15];
  const float* dec_c2_w = (const float*)d_in[16];
  const float* dec_c2_b = (const float*)d_in[17];
  const float* dec_c3_w = (const float*)d_in[18];
  const float* dec_c3_b = (const float*)d_in[19];

  // output: [loss(1)] [x_re(32*65536)] [perplexity(1)] [qn(32*262144)]
  float* out      = (float*)d_out;
  float* loss_out = out;
  float* xre_out  = out + 1;
  float* perp_out = out + 1 + 2097152;
  float* qn_out   = out + 2 + 2097152;

  float* sum_sq = (float*)d_ws;
  int*   hist   = (int*)d_ws + 1;
  float* base   = (float*)d_ws + 256;

  // per-sample scratch floats: C 524288 + D 262144 + B 524288 = 1,310,720 (5MB)
  const size_t PER_C = 524288, PER_D = 262144, PER_B = 524288;
  const size_t PER_SAMPLE = PER_C + PER_D + PER_B;

  long long avail = (long long)(ws_size / 4) - 256;
  int chunk = (int)(avail / (long long)PER_SAMPLE);
  if (chunk > 32) chunk = 32;
  if (chunk < 1)  chunk = 1;

  hipLaunchKernelGGL(init_k, dim3(1), dim3(128), 0, stream, sum_sq, hist);

  for (int b0 = 0; b0 < 32; b0 += chunk) {
    int cur = (32 - b0 < chunk) ? (32 - b0) : chunk;

    float* Cb = base;                         // cur * 524288  (c,128,64,64)
    float* Db = Cb + (size_t)chunk * PER_C;   // cur * 262144  (c,64,64,64)
    float* Bb = Db + (size_t)chunk * PER_D;   // cur * 524288  (c,128,64,64)
    // dec_c2 bf16 output overlays the (then dead) C slot: cur*1048576 bf16 = 2MB/sample
    __hip_bfloat16* Ab = (__hip_bfloat16*)Cb;

    const float* xC  = x + (size_t)b0 * 65536;
    float* qnC  = qn_out + (size_t)b0 * 262144;
    float* xreC = xre_out + (size_t)b0 * 65536;

    // ---- encoder ----
    hipLaunchKernelGGL(enc12_t, dim3(16, 8, cur), dim3(256), 0, stream,
                       xC, enc_c1_w, enc_c1_b, enc_c2_w, enc_c2_b, Bb);
    hipLaunchKernelGGL((conv3_t<128, 128, 4, 8, 0, true, false, false>),
                       dim3(16, 16, cur), dim3(256), 0, stream,
                       Bb, enc_c3_w, enc_c3_b, Cb);

    // encoder residual block (2 iters, shared weights)
    hipLaunchKernelGGL((conv3_t<128, 64, 2, 4, 0, false, true, true>),
                       dim3(32, 16, cur), dim3(128), 0, stream,
                       Cb, enc_r1_w, nullptr, Db);
    hipLaunchKernelGGL(res_add_k, dim3(16, 16, cur), dim3(256), 0, stream,
                       Cb, Db, enc_r2_w, Bb);
    hipLaunchKernelGGL((conv3_t<128, 64, 2, 4, 0, false, true, true>),
                       dim3(32, 16, cur), dim3(128), 0, stream,
                       Bb, enc_r1_w, nullptr, Db);
    hipLaunchKernelGGL(res_add_k, dim3(16, 16, cur), dim3(256), 0, stream,
                       Bb, Db, enc_r2_w, Cb);

    // ---- fused pre-VQ conv + VQ: q -> D slot (dead), then d2d to qn ----
    hipLaunchKernelGGL(vq_k, dim3(cur * 16), dim3(256), 0, stream,
                       Cb, vqc_w, vqc_b, emb, Db, sum_sq, hist);
    hipMemcpyAsync(qnC, Db, (size_t)cur * 262144 * 4,
                   hipMemcpyDeviceToDevice, stream);

    // ---- decoder ----
    hipLaunchKernelGGL((conv3_t<64, 128, 4, 8, 1, true, false, false>),
                       dim3(16, 16, cur), dim3(256), 0, stream,
                       qnC, dec_c1_w, dec_c1_b, Bb);

    hipLaunchKernelGGL((conv3_t<128, 64, 2, 4, 0, false, true, true>),
                       dim3(32, 16, cur), dim3(128), 0, stream,
                       Bb, dec_r1_w, nullptr, Db);
    hipLaunchKernelGGL(res_add_k, dim3(16, 16, cur), dim3(256), 0, stream,
                       Bb, Db, dec_r2_w, Cb);
    hipLaunchKernelGGL((conv3_t<128, 64, 2, 4, 0, false, true, true>),
                       dim3(32, 16, cur), dim3(128), 0, stream,
                       Cb, dec_r1_w, nullptr, Db);
    hipLaunchKernelGGL(res_add_k, dim3(16, 16, cur), dim3(256), 0, stream,
                       Cb, Db, dec_r2_w, Bb);

    // dec_c2 (relu in+out) -> bf16 A in dead C slot; then dec_c3 + tanh
    hipLaunchKernelGGL(dec2p_t, dim3(16, 16, cur), dim3(256), 0, stream,
                       Bb, dec_c2_w, dec_c2_b, Ab);
    hipLaunchKernelGGL(dec3_t, dim3(64, 1, cur), dim3(256), 0, stream,
                       Ab, dec_c3_w, dec_c3_b, xreC);
  }

  hipLaunchKernelGGL(finalize_k, dim3(1), dim3(64), 0, stream,
                     sum_sq, hist, loss_out, perp_out);
}

// Round 6
// 6509.692 us; speedup vs baseline: 1.6535x; 1.6535x over previous
//
#include <hip/hip_runtime.h>
#include <cmath>

// ---------------------------------------------------------------------------
// VQ-VAE forward, round 6.
// Evidence: WRITE_SIZE decoding proves ws >= 264.2 MB and chunk was already 32
// (single pass). fp32 VALU path is capped ~50 TF effective => 10.7ms.
// Plan: encoder stays fp32 (protects VQ argmin / perplexity) but un-fused
// (enc1 -> fp32 A buffer -> enc_c2; kills enc12's recompute + 64KB-LDS cap).
// Decoder (dec_c1, r1 x2, res x2, dec_c2) -> bf16 MFMA tap-GEMMs over padded
// HWC activations; weights repacked on-device to [tap][oc][ic] bf16.
// dec_c2 = 4 parity 2x2 tap-GEMMs; dec_c3 reads parity planes.
// Workspace pool (byte offsets after 1KB header), peak 240.6MB <= 264.2 proven:
//   A   fp32 0..134.2M (dead after enc_c2)     B fp32 134.2..201.3M
//   C   fp32 0..67.1M (over dead A)            D fp32 201.3..234.9M
//   Dq  bf16 67.1..85.0M   Y1 bf16 134.2..169.9M   S bf16 170.0..187.8M
//   Y2  bf16 90.0..125.7M  P4 bf16 0..71.4M (dec2 out; after C,Dq dead)
//   W   bf16 240.0..240.6M (repacked weights; overlaps nothing)
// ---------------------------------------------------------------------------

static constexpr int NPOS  = 131072;
static constexpr long long NELEM = 8388608;

typedef __attribute__((ext_vector_type(8))) short short8;
typedef __attribute__((ext_vector_type(4))) float f32x4;

__device__ __forceinline__ unsigned short f2bf(float f) {
  unsigned int x = __float_as_uint(f);
  unsigned int r = (x + 0x7fffu + ((x >> 16) & 1u)) >> 16;
  return (unsigned short)r;
}
__device__ __forceinline__ float bf2f(unsigned short u) {
  return __uint_as_float(((unsigned int)u) << 16);
}

// ======== enc_c1: 4x4 s2 p1, (b,1,256,256) -> fp32 A (b,64,128,128) ========
__global__ void __launch_bounds__(256) enc1_t(
    const float* __restrict__ in, const float* __restrict__ w,
    const float* __restrict__ bias, float* __restrict__ out)
{
  constexpr int OCB = 16;
  int tid = threadIdx.x;
  int rr = tid >> 7, ox = tid & 127;
  int oy  = blockIdx.x * 2 + rr;
  int oc0 = blockIdx.y * OCB;
  int b   = blockIdx.z;

  const float* pl = in + (size_t)b * 65536;
  float v[16];
  #pragma unroll
  for (int ky = 0; ky < 4; ++ky) {
    int iy = 2 * oy - 1 + ky;
    #pragma unroll
    for (int kx = 0; kx < 4; ++kx) {
      int ix = 2 * ox - 1 + kx;
      v[ky * 4 + kx] = (iy >= 0 && iy < 256 && ix >= 0 && ix < 256)
                       ? pl[iy * 256 + ix] : 0.f;
    }
  }
  float acc[OCB];
  #pragma unroll
  for (int o = 0; o < OCB; ++o) acc[o] = bias[oc0 + o];
  #pragma unroll
  for (int t = 0; t < 16; ++t)
    #pragma unroll
    for (int o = 0; o < OCB; ++o)
      acc[o] += v[t] * w[(size_t)(oc0 + o) * 16 + t];

  float* ob = out + ((size_t)b * 64 + oc0) * 16384 + oy * 128 + ox;
  #pragma unroll
  for (int o = 0; o < OCB; ++o)
    ob[(size_t)o * 16384] = fmaxf(acc[o], 0.f);
}

// ======== enc_c2: 4x4 s2 p1, fp32 A -> fp32 B (b,128,64,64), ICB=2 =========
__global__ void __launch_bounds__(256) conv4s2_t(
    const float* __restrict__ in, const float* __restrict__ w,
    const float* __restrict__ bias, float* __restrict__ out)
{
  constexpr int IC = 64, OC = 128, OCB = 16, ICB = 2;
  __shared__ float lds[2][ICB][1300];
  int tid = threadIdx.x;
  int r = tid >> 6, c = tid & 63;
  int ty  = blockIdx.x * 4;
  int oc0 = blockIdx.y * OCB;
  int b   = blockIdx.z;

  const float* inb = in + (size_t)b * IC * 16384;
  float acc[OCB];
  #pragma unroll
  for (int o = 0; o < OCB; ++o) acc[o] = bias[oc0 + o];

  for (int icb = 0; icb < IC / ICB; ++icb) {
    float (*buf)[1300] = lds[icb & 1];
    #pragma unroll
    for (int ii = 0; ii < ICB; ++ii) {
      const float* pl = inb + (size_t)(icb * ICB + ii) * 16384;
      for (int idx = tid; idx < 1300; idx += 256) {
        int rr = idx / 130, cc = idx - rr * 130;
        int iy = ty * 2 + rr - 1, ix = cc - 1;
        float v = 0.f;
        if (iy >= 0 && iy < 128 && ix >= 0 && ix < 128) v = pl[iy * 128 + ix];
        buf[ii][idx] = v;
      }
    }
    __syncthreads();

    #pragma unroll
    for (int ii = 0; ii < ICB; ++ii) {
      int ic = icb * ICB + ii;
      float v[16];
      #pragma unroll
      for (int ky = 0; ky < 4; ++ky)
        #pragma unroll
        for (int kx = 0; kx < 4; ++kx)
          v[ky * 4 + kx] = buf[ii][(2 * r + ky) * 130 + 2 * c + kx];
      #pragma unroll
      for (int t = 0; t < 16; ++t)
        #pragma unroll
        for (int o = 0; o < OCB; ++o)
          acc[o] += v[t] * w[((size_t)(oc0 + o) * IC + ic) * 16 + t];
    }
  }

  float* ob = out + ((size_t)b * OC + oc0) * 4096 + (ty + r) * 64 + c;
  #pragma unroll
  for (int o = 0; o < OCB; ++o)
    ob[(size_t)o * 4096] = fmaxf(acc[o], 0.f);
}

// ======== fp32 3x3 s1 p1 conv at 64x64 (encoder) ===========================
template<int IC, int OC, int TR, int OCB, int WMODE, bool BIAS, bool RELU_IN, bool RELU_OUT>
__global__ void __launch_bounds__(TR * 64) conv3_t(
    const float* __restrict__ in, const float* __restrict__ w,
    const float* __restrict__ bias, float* __restrict__ out)
{
  constexpr int ICB = 8;
  constexpr int NE = (TR + 2) * 66;
  __shared__ float lds[2][ICB][NE];
  int tid = threadIdx.x;
  int r = tid >> 6, c = tid & 63;
  int ty  = blockIdx.x * TR;
  int oc0 = blockIdx.y * OCB;
  int b   = blockIdx.z;

  const float* inb = in + (size_t)b * IC * 4096;
  float acc[OCB];
  #pragma unroll
  for (int o = 0; o < OCB; ++o) acc[o] = BIAS ? bias[oc0 + o] : 0.f;

  for (int icb = 0; icb < IC / ICB; ++icb) {
    float (*buf)[NE] = lds[icb & 1];
    #pragma unroll
    for (int ii = 0; ii < ICB; ++ii) {
      const float* pl = inb + (size_t)(icb * ICB + ii) * 4096;
      for (int idx = tid; idx < NE; idx += TR * 64) {
        int rr = idx / 66, cc = idx - rr * 66;
        int iy = ty + rr - 1, ix = cc - 1;
        float v = 0.f;
        if (iy >= 0 && iy < 64 && ix >= 0 && ix < 64) {
          v = pl[iy * 64 + ix];
          if (RELU_IN) v = fmaxf(v, 0.f);
        }
        buf[ii][idx] = v;
      }
    }
    __syncthreads();

    #pragma unroll
    for (int ii = 0; ii < ICB; ++ii) {
      int ic = icb * ICB + ii;
      float v[9];
      #pragma unroll
      for (int ky = 0; ky < 3; ++ky)
        #pragma unroll
        for (int kx = 0; kx < 3; ++kx)
          v[ky * 3 + kx] = buf[ii][(r + ky) * 66 + c + kx];

      #pragma unroll
      for (int t = 0; t < 9; ++t) {
        int ky = t / 3, kx = t - ky * 3;
        #pragma unroll
        for (int o = 0; o < OCB; ++o) {
          float wt = (WMODE == 0)
            ? w[((size_t)(oc0 + o) * IC + ic) * 9 + t]
            : w[((size_t)ic * OC + (oc0 + o)) * 9 + (2 - ky) * 3 + (2 - kx)];
          acc[o] += v[t] * wt;
        }
      }
    }
  }

  float* ob = out + ((size_t)b * OC + oc0) * 4096 + (ty + r) * 64 + c;
  #pragma unroll
  for (int o = 0; o < OCB; ++o) {
    float a = acc[o];
    if (RELU_OUT) a = fmaxf(a, 0.f);
    ob[(size_t)o * 4096] = a;
  }
}

// ======== fp32 res tail: out = relu(x) + w2 @ h (1x1), OCB=8 ===============
__global__ void __launch_bounds__(256) res_add_k(
    const float* __restrict__ x, const float* __restrict__ h,
    const float* __restrict__ w2, float* __restrict__ out)
{
  int p   = blockIdx.x * 256 + threadIdx.x;
  int oc0 = blockIdx.y * 8;
  int b   = blockIdx.z;
  const float* xb = x + ((size_t)b * 128 + oc0) * 4096 + p;
  float acc[8];
  #pragma unroll
  for (int o = 0; o < 8; ++o) acc[o] = fmaxf(xb[(size_t)o * 4096], 0.f);
  const float* hb = h + (size_t)b * 64 * 4096 + p;
  #pragma unroll 4
  for (int ic = 0; ic < 64; ++ic) {
    float v = hb[(size_t)ic * 4096];
    #pragma unroll
    for (int o = 0; o < 8; ++o)
      acc[o] += w2[(oc0 + o) * 64 + ic] * v;
  }
  float* ob = out + ((size_t)b * 128 + oc0) * 4096 + p;
  #pragma unroll
  for (int o = 0; o < 8; ++o) ob[(size_t)o * 4096] = acc[o];
}

// ======== fused pre-VQ 1x1 conv + VQ: fp32 in; qn fp32 + Dq bf16-HWC =======
__global__ void __launch_bounds__(256) vq_k(
    const float* __restrict__ xres, const float* __restrict__ vw,
    const float* __restrict__ vb, const float* __restrict__ emb,
    float* __restrict__ qn, unsigned short* __restrict__ dqb,
    float* __restrict__ sum_sq, int* __restrict__ hist)
{
  int tid = threadIdx.x;
  int n = blockIdx.x * 256 + tid;
  int b = n >> 12;
  int pos = n & 4095;
  int u = pos >> 6, v2 = pos & 63;

  float z[64];
  #pragma unroll
  for (int k = 0; k < 64; ++k) z[k] = vb[k];

  const float* xb = xres + (size_t)b * 128 * 4096 + pos;
  for (int c = 0; c < 128; ++c) {
    float v = fmaxf(xb[(size_t)c * 4096], 0.f);
    #pragma unroll
    for (int k = 0; k < 64; ++k) z[k] += v * vw[k * 128 + c];
  }

  float z2 = 0.f;
  #pragma unroll
  for (int d = 0; d < 64; ++d) z2 += z[d] * z[d];

  float best = INFINITY;
  int bidx = 0;
  for (int k = 0; k < 64; ++k) {
    float dot = 0.f, e2 = 0.f;
    #pragma unroll
    for (int d = 0; d < 64; ++d) {
      float e = emb[k * 64 + d];
      dot += z[d] * e;
      e2  += e * e;
    }
    float dist = z2 + e2 - 2.f * dot;
    if (dist < best) { best = dist; bidx = k; }
  }

  float sq = 0.f;
  const float* eb = emb + bidx * 64;
  float* qb = qn + (size_t)b * 262144 + pos;
  unsigned short* dq = dqb + (size_t)b * 278784 + ((size_t)(u + 1) * 66 + (v2 + 1)) * 64;
  #pragma unroll
  for (int d = 0; d < 64; ++d) {
    float e = eb[d];
    float df = e - z[d];
    sq += df * df;
    qb[(size_t)d * 4096] = e;
    dq[d] = f2bf(e);
  }

  __shared__ float red[256];
  __shared__ int lh[64];
  red[tid] = sq;
  if (tid < 64) lh[tid] = 0;
  __syncthreads();
  atomicAdd(&lh[bidx], 1);
  for (int s = 128; s > 0; s >>= 1) {
    if (tid < s) red[tid] += red[tid + s];
    __syncthreads();
  }
  if (tid == 0) atomicAdd(sum_sq, red[0]);
  if (tid < 64) atomicAdd(&hist[tid], lh[tid]);
}

// ======== bf16 MFMA tap-GEMM conv ==========================================
// in: padded HWC bf16 (66x66 plane, IC ch). wt: [tap][OC][IC] bf16.
// out: padded HWC bf16 (OC ch). MODE 0: 3x3 (9 taps, dy=t/3-1,dx=t%3-1).
// MODE 1: dec2 parity (4 taps, dy=ry-(t>>1), dx=rx-(t&1)). MODE 2: 1x1.
// MFMA layouts (cdna4 guide, m89/m91-verified): A[m=lane&15][k=quad*8+j],
// B[k=quad*8+j][n=lane&15], D: col=lane&15 (n), row=quad*4+reg (m).
template<int IC, int OC, int MODE, bool HAS_BIAS, bool HAS_SKIP, bool RELU>
__global__ void __launch_bounds__(256) mfma_conv(
    const unsigned short* __restrict__ in, const unsigned short* __restrict__ wt,
    const float* __restrict__ bias, const unsigned short* __restrict__ skip,
    unsigned short* __restrict__ out, int ry, int rx, int in_ss, int out_ss)
{
  constexpr int OM = OC / 16;
  constexpr int NT = (MODE == 0) ? 9 : ((MODE == 1) ? 4 : 1);
  const int tid = threadIdx.x;
  const int wv = tid >> 6, lane = tid & 63;
  const int quad = lane >> 4, l15 = lane & 15;
  const int b = blockIdx.z;
  const int y0 = blockIdx.x * 2;
  const int t0 = wv * 2, t1 = t0 + 1;
  const int yA = y0 + (t0 >> 2), xA = ((t0 & 3) << 4) + l15;
  const int yB = y0 + (t1 >> 2), xB = ((t1 & 3) << 4) + l15;
  const unsigned short* inb = in + (size_t)b * (size_t)in_ss;

  f32x4 acc[OM][2];
  #pragma unroll
  for (int m = 0; m < OM; ++m) {
    const int oc0 = m * 16 + quad * 4;
    f32x4 ini0 = {0.f, 0.f, 0.f, 0.f};
    if (HAS_BIAS) {
      float4 bs = *(const float4*)(bias + oc0);
      ini0[0] = bs.x; ini0[1] = bs.y; ini0[2] = bs.z; ini0[3] = bs.w;
    }
    f32x4 ini1 = ini0;
    if (HAS_SKIP) {
      const unsigned short* s0 = skip + (size_t)b * (size_t)out_ss
                               + ((size_t)(yA + 1) * 66 + (xA + 1)) * OC + oc0;
      const unsigned short* s1 = skip + (size_t)b * (size_t)out_ss
                               + ((size_t)(yB + 1) * 66 + (xB + 1)) * OC + oc0;
      #pragma unroll
      for (int r = 0; r < 4; ++r) { ini0[r] += bf2f(s0[r]); ini1[r] += bf2f(s1[r]); }
    }
    acc[m][0] = ini0; acc[m][1] = ini1;
  }

  #pragma unroll
  for (int t = 0; t < NT; ++t) {
    const int dy = (MODE == 0) ? (t / 3 - 1) : ((MODE == 1) ? (ry - (t >> 1)) : 0);
    const int dx = (MODE == 0) ? (t % 3 - 1) : ((MODE == 1) ? (rx - (t & 1)) : 0);
    const unsigned short* rA = inb + ((size_t)(yA + dy + 1) * 66 + (xA + dx + 1)) * IC + quad * 8;
    const unsigned short* rB = inb + ((size_t)(yB + dy + 1) * 66 + (xB + dx + 1)) * IC + quad * 8;
    const unsigned short* wr = wt + (size_t)t * OC * IC + (size_t)l15 * IC + quad * 8;
    #pragma unroll
    for (int k0 = 0; k0 < IC; k0 += 32) {
      short8 fb0 = *(const short8*)(rA + k0);
      short8 fb1 = *(const short8*)(rB + k0);
      #pragma unroll
      for (int m = 0; m < OM; ++m) {
        short8 fa = *(const short8*)(wr + (size_t)m * 16 * IC + k0);
        acc[m][0] = __builtin_amdgcn_mfma_f32_16x16x32_bf16(fa, fb0, acc[m][0], 0, 0, 0);
        acc[m][1] = __builtin_amdgcn_mfma_f32_16x16x32_bf16(fa, fb1, acc[m][1], 0, 0, 0);
      }
    }
  }

  #pragma unroll
  for (int m = 0; m < OM; ++m) {
    const int oc0 = m * 16 + quad * 4;
    unsigned short* o0 = out + (size_t)b * (size_t)out_ss
                       + ((size_t)(yA + 1) * 66 + (xA + 1)) * OC + oc0;
    unsigned short* o1 = out + (size_t)b * (size_t)out_ss
                       + ((size_t)(yB + 1) * 66 + (xB + 1)) * OC + oc0;
    ushort4 u0, u1;
    float v;
    v = acc[m][0][0]; if (RELU) v = fmaxf(v, 0.f); u0.x = f2bf(v);
    v = acc[m][0][1]; if (RELU) v = fmaxf(v, 0.f); u0.y = f2bf(v);
    v = acc[m][0][2]; if (RELU) v = fmaxf(v, 0.f); u0.z = f2bf(v);
    v = acc[m][0][3]; if (RELU) v = fmaxf(v, 0.f); u0.w = f2bf(v);
    v = acc[m][1][0]; if (RELU) v = fmaxf(v, 0.f); u1.x = f2bf(v);
    v = acc[m][1][1]; if (RELU) v = fmaxf(v, 0.f); u1.y = f2bf(v);
    v = acc[m][1][2]; if (RELU) v = fmaxf(v, 0.f); u1.z = f2bf(v);
    v = acc[m][1][3]; if (RELU) v = fmaxf(v, 0.f); u1.w = f2bf(v);
    *(ushort4*)o0 = u0;
    *(ushort4*)o1 = u1;
  }
}

// ======== dec_c3: transposed 4x4 s2 p1, bf16 parity planes -> fp32 x_re ====
__global__ void __launch_bounds__(256) dec3_t(
    const unsigned short* __restrict__ p4, const float* __restrict__ w,
    const float* __restrict__ bias, float* __restrict__ out)
{
  constexpr int ICB = 4;
  __shared__ float lds[2][ICB][520];   // 4 rows x 130 cols
  int tid = threadIdx.x;
  int yr = tid >> 7, x = tid & 127;
  int y0 = blockIdx.x * 2;
  int y  = y0 + yr;
  int b  = blockIdx.z;

  const int kt[2][2] = {{1, 3}, {0, 2}};
  const int dt[2][2] = {{1, 0}, {2, 1}};

  float acc[4] = {0.f, 0.f, 0.f, 0.f};

  for (int icb = 0; icb < 64 / ICB; ++icb) {
    float (*buf)[520] = lds[icb & 1];
    #pragma unroll
    for (int ii = 0; ii < ICB; ++ii) {
      int ic = icb * ICB + ii;
      for (int idx = tid; idx < 520; idx += 256) {
        int r2 = idx / 130, c2 = idx - r2 * 130;
        int iy = y0 + r2 - 1;             // -1..128
        int ix = c2 - 1;                  // -1..128
        int py = iy & 1, px = ix & 1;
        int u = iy >> 1, v = ix >> 1;     // arithmetic shift: -1 -> -1 (pad)
        const unsigned short* pl = p4
            + ((size_t)(b * 4 + py * 2 + px) * 4356
               + (size_t)(u + 1) * 66 + (v + 1)) * 64 + ic;
        buf[ii][idx] = bf2f(*pl);
      }
    }
    __syncthreads();

    #pragma unroll
    for (int ii = 0; ii < ICB; ++ii) {
      int ic = icb * ICB + ii;
      float v[9];
      #pragma unroll
      for (int dy = 0; dy < 3; ++dy)
        #pragma unroll
        for (int dx = 0; dx < 3; ++dx)
          v[dy * 3 + dx] = buf[ii][(yr + dy) * 130 + x + dx];
      const float* wp = w + (size_t)ic * 16;
      #pragma unroll
      for (int ry = 0; ry < 2; ++ry)
        #pragma unroll
        for (int rx = 0; rx < 2; ++rx)
          #pragma unroll
          for (int a = 0; a < 2; ++a)
            #pragma unroll
            for (int c2 = 0; c2 < 2; ++c2)
              acc[ry * 2 + rx] += v[dt[ry][a] * 3 + dt[rx][c2]]
                                * wp[kt[ry][a] * 4 + kt[rx][c2]];
    }
  }

  float b0 = bias[0];
  float* ob = out + (size_t)b * 65536;
  #pragma unroll
  for (int ry = 0; ry < 2; ++ry)
    #pragma unroll
    for (int rx = 0; rx < 2; ++rx)
      ob[(2 * y + ry) * 256 + 2 * x + rx] = tanhf(acc[ry * 2 + rx] + b0);
}

// ======== aux: zero the pad ring of a padded-HWC bf16 buffer ===============
// grid.x = nplanes; icl = log2(ic)
__global__ void ring_zero_k(unsigned short* __restrict__ buf, int ic, int icl)
{
  unsigned short* p = buf + (size_t)blockIdx.x * 4356 * ic;
  int total = 260 * ic;
  for (int idx = threadIdx.x; idx < total; idx += 256) {
    int cell = idx >> icl;
    int e = idx & (ic - 1);
    int row, col;
    if (cell < 66)       { row = 0;  col = cell; }
    else if (cell < 132) { row = 65; col = cell - 66; }
    else if (cell < 196) { row = cell - 132 + 1; col = 0; }
    else                 { row = cell - 196 + 1; col = 65; }
    p[(size_t)(row * 66 + col) * ic + e] = 0;
  }
}

// ======== aux: repack decoder weights to bf16 [tap][oc][ic] ================
// W layout: [0,73728) dec_c1 9x128x64 | [73728,147456) r1 9x64x128 |
// [147456,155648) r2 128x64 | [155648,286720) dec2 [p][t2][64][128]
__global__ void repack_k(const float* __restrict__ c1w, const float* __restrict__ r1w,
                         const float* __restrict__ r2w, const float* __restrict__ c2w,
                         unsigned short* __restrict__ W)
{
  int idx = blockIdx.x * 256 + threadIdx.x;
  if (idx >= 286720) return;
  float val;
  if (idx < 73728) {                       // dec_c1: transposed 3x3, flipped
    int t = idx / 8192, rem = idx & 8191;
    int oc = rem >> 6, ic = rem & 63;
    int ky = t / 3, kx = t - ky * 3;
    val = c1w[((ic * 128 + oc) * 3 + (2 - ky)) * 3 + (2 - kx)];
  } else if (idx < 147456) {               // r1: OIHW direct
    int j = idx - 73728;
    int t = j / 8192, rem = j & 8191;
    int oc = rem >> 7, ic = rem & 127;
    int ky = t / 3, kx = t - ky * 3;
    val = r1w[((oc * 128 + ic) * 3 + ky) * 3 + kx];
  } else if (idx < 155648) {               // r2: 1x1 OIHW
    int j = idx - 147456;
    int oc = j >> 6, ic = j & 63;
    val = r2w[oc * 64 + ic];
  } else {                                 // dec2 parity: w (Cin=128,Cout=64,4,4)
    int j = idx - 155648;
    int p = j >> 15;                       // /32768
    int t2 = (j >> 13) & 3;                // /8192 %4
    int oc = (j >> 7) & 63;
    int ic = j & 127;
    int ry = p >> 1, rx = p & 1;
    int aY = t2 >> 1, aX = t2 & 1;
    int ky = aY ? (3 - ry) : (1 - ry);
    int kx = aX ? (3 - rx) : (1 - rx);
    val = c2w[((ic * 64 + oc) * 4 + ky) * 4 + kx];
  }
  W[idx] = f2bf(val);
}

// ======== scratch init + scalar finalize ===================================
__global__ void init_k(float* sum_sq, int* hist)
{
  int t = threadIdx.x;
  if (t == 0) sum_sq[0] = 0.f;
  if (t < 64) hist[t] = 0;
}

__global__ void finalize_k(const float* __restrict__ sum_sq, const int* __restrict__ hist,
                           float* __restrict__ loss_out, float* __restrict__ perp_out)
{
  if (threadIdx.x == 0) {
    float mse = sum_sq[0] / (float)NELEM;
    loss_out[0] = 1.25f * mse;
    float ent = 0.f;
    for (int k = 0; k < 64; ++k) {
      float p = (float)hist[k] / (float)NPOS;
      ent += p * logf(p + 1e-10f);
    }
    perp_out[0] = expf(-ent);
  }
}

// ---------------------------------------------------------------------------
extern "C" void kernel_launch(void* const* d_in, const int* in_sizes, int n_in,
                              void* d_out, int out_size, void* d_ws, size_t ws_size,
                              hipStream_t stream)
{
  const float* x        = (const float*)d_in[0];
  const float* enc_c1_w = (const float*)d_in[1];
  const float* enc_c1_b = (const float*)d_in[2];
  const float* enc_c2_w = (const float*)d_in[3];
  const float* enc_c2_b = (const float*)d_in[4];
  const float* enc_c3_w = (const float*)d_in[5];
  const float* enc_c3_b = (const float*)d_in[6];
  const float* enc_r1_w = (const float*)d_in[7];
  const float* enc_r2_w = (const float*)d_in[8];
  const float* vqc_w    = (const float*)d_in[9];
  const float* vqc_b    = (const float*)d_in[10];
  const float* emb      = (const float*)d_in[11];
  const float* dec_c1_w = (const float*)d_in[12];
  const float* dec_c1_b = (const float*)d_in[13];
  const float* dec_r1_w = (const float*)d_in[14];
  const float* dec_r2_w = (const float*)d_in[15];
  const float* dec_c2_w = (const float*)d_in[16];
  const float* dec_c2_b = (const float*)d_in[17];
  const float* dec_c3_w = (const float*)d_in[18];
  const float* dec_c3_b = (const float*)d_in[19];

  // output: [loss(1)] [x_re(32*65536)] [perplexity(1)] [qn(32*262144)]
  float* out      = (float*)d_out;
  float* loss_out = out;
  float* xre_out  = out + 1;
  float* perp_out = out + 1 + 2097152;
  float* qn_out   = out + 2 + 2097152;

  float* sum_sq = (float*)d_ws;
  int*   hist   = (int*)d_ws + 1;
  char*  pool   = (char*)d_ws + 1024;

  // pool layout (see header comment)
  float*          A  = (float*)(pool + 0);
  float*          B  = (float*)(pool + 134217728);
  float*          C  = (float*)(pool + 0);
  float*          D  = (float*)(pool + 201326592);
  unsigned short* Dq = (unsigned short*)(pool + 67108864);
  unsigned short* Y1 = (unsigned short*)(pool + 134217728);
  unsigned short* S  = (unsigned short*)(pool + 170000000);
  unsigned short* Y2 = (unsigned short*)(pool + 90000000);
  unsigned short* P4 = (unsigned short*)(pool + 0);
  unsigned short* W  = (unsigned short*)(pool + 240000000);

  const int SS64  = 278784;    // 4356*64  (padded HWC, 64 ch)
  const int SS128 = 557568;    // 4356*128
  const int SSP4  = 1115136;   // 4*4356*64

  hipLaunchKernelGGL(init_k, dim3(1), dim3(128), 0, stream, sum_sq, hist);
  hipLaunchKernelGGL(repack_k, dim3(1120), dim3(256), 0, stream,
                     dec_c1_w, dec_r1_w, dec_r2_w, dec_c2_w, W);

  // ---- encoder (fp32, protects VQ precision) ----
  hipLaunchKernelGGL(enc1_t, dim3(64, 4, 32), dim3(256), 0, stream,
                     x, enc_c1_w, enc_c1_b, A);
  hipLaunchKernelGGL(conv4s2_t, dim3(16, 8, 32), dim3(256), 0, stream,
                     A, enc_c2_w, enc_c2_b, B);
  hipLaunchKernelGGL((conv3_t<128, 128, 4, 8, 0, true, false, false>),
                     dim3(16, 16, 32), dim3(256), 0, stream,
                     B, enc_c3_w, enc_c3_b, C);
  hipLaunchKernelGGL((conv3_t<128, 64, 2, 4, 0, false, true, true>),
                     dim3(32, 16, 32), dim3(128), 0, stream,
                     C, enc_r1_w, nullptr, D);
  hipLaunchKernelGGL(res_add_k, dim3(16, 16, 32), dim3(256), 0, stream,
                     C, D, enc_r2_w, B);
  hipLaunchKernelGGL((conv3_t<128, 64, 2, 4, 0, false, true, true>),
                     dim3(32, 16, 32), dim3(128), 0, stream,
                     B, enc_r1_w, nullptr, D);
  hipLaunchKernelGGL(res_add_k, dim3(16, 16, 32), dim3(256), 0, stream,
                     B, D, enc_r2_w, C);

  // ---- VQ: qn fp32 out + bf16 padded-HWC q for decoder ----
  hipLaunchKernelGGL(vq_k, dim3(512), dim3(256), 0, stream,
                     C, vqc_w, vqc_b, emb, qn_out, Dq, sum_sq, hist);

  // ---- aux: zero pad rings (regions dead post-vq) ----
  hipLaunchKernelGGL(ring_zero_k, dim3(32), dim3(256), 0, stream, Dq, 64, 6);
  hipLaunchKernelGGL(ring_zero_k, dim3(32), dim3(256), 0, stream, Y1, 128, 7);
  hipLaunchKernelGGL(ring_zero_k, dim3(32), dim3(256), 0, stream, Y2, 128, 7);
  hipLaunchKernelGGL(ring_zero_k, dim3(32), dim3(256), 0, stream, S, 64, 6);

  // ---- decoder (bf16 MFMA) ----
  hipLaunchKernelGGL((mfma_conv<64, 128, 0, true, false, true>),
                     dim3(32, 1, 32), dim3(256), 0, stream,
                     Dq, W, dec_c1_b, nullptr, Y1, 0, 0, SS64, SS128);
  hipLaunchKernelGGL((mfma_conv<128, 64, 0, false, false, true>),
                     dim3(32, 1, 32), dim3(256), 0, stream,
                     Y1, W + 73728, nullptr, nullptr, S, 0, 0, SS128, SS64);
  hipLaunchKernelGGL((mfma_conv<64, 128, 2, false, true, true>),
                     dim3(32, 1, 32), dim3(256), 0, stream,
                     S, W + 147456, nullptr, Y1, Y2, 0, 0, SS64, SS128);
  hipLaunchKernelGGL((mfma_conv<128, 64, 0, false, false, true>),
                     dim3(32, 1, 32), dim3(256), 0, stream,
                     Y2, W + 73728, nullptr, nullptr, S, 0, 0, SS128, SS64);
  hipLaunchKernelGGL((mfma_conv<64, 128, 2, false, true, true>),
                     dim3(32, 1, 32), dim3(256), 0, stream,
                     S, W + 147456, nullptr, Y2, Y1, 0, 0, SS64, SS128);

  // P4 rings (region 0..71.4M dead: C, Dq both consumed)
  hipLaunchKernelGGL(ring_zero_k, dim3(128), dim3(256), 0, stream, P4, 64, 6);

  // dec_c2 as 4 parity tap-GEMMs
  for (int p = 0; p < 4; ++p) {
    hipLaunchKernelGGL((mfma_conv<128, 64, 1, true, false, true>),
                       dim3(32, 1, 32), dim3(256), 0, stream,
                       Y1, W + 155648 + p * 32768, dec_c2_b, nullptr,
                       P4 + (size_t)p * 4356 * 64, p >> 1, p & 1, SS128, SSP4);
  }

  hipLaunchKernelGGL(dec3_t, dim3(64, 1, 32), dim3(256), 0, stream,
                     P4, dec_c3_w, dec_c3_b, xre_out);

  hipLaunchKernelGGL(finalize_k, dim3(1), dim3(64), 0, stream,
                     sum_sq, hist, loss_out, perp_out);
}

// Round 7
// 4219.093 us; speedup vs baseline: 2.5512x; 1.5429x over previous
//
#include <hip/hip_runtime.h>
#include <cmath>

// ---------------------------------------------------------------------------
// VQ-VAE forward, round 7.
// Round-6: dec3_t was fetch-bound (4.2GB FETCH vs 71MB buffer, 60x over-fetch
// from 2-byte strided HWC gathers). Fix: LDS-free dec3 with short8 (16B)
// channel-octet loads, 9 hoisted base pointers. Encoder stays fp32 (bf16
// would flip ~1% of VQ argmins => delta-perplexity ~0.5 >> 0.147 threshold);
// conv3_t OCB 8->16 doubles FMA:LDS ratio (144 FMA : 9 ds_read per ic).
// Decoder unchanged (bf16 MFMA tap-GEMMs, verified round 6).
// ---------------------------------------------------------------------------

static constexpr int NPOS  = 131072;
static constexpr long long NELEM = 8388608;

typedef __attribute__((ext_vector_type(8))) short short8;
typedef __attribute__((ext_vector_type(8))) unsigned short ushort8;
typedef __attribute__((ext_vector_type(4))) float f32x4;

__device__ __forceinline__ unsigned short f2bf(float f) {
  unsigned int x = __float_as_uint(f);
  unsigned int r = (x + 0x7fffu + ((x >> 16) & 1u)) >> 16;
  return (unsigned short)r;
}
__device__ __forceinline__ float bf2f(unsigned short u) {
  return __uint_as_float(((unsigned int)u) << 16);
}

// ======== enc_c1: 4x4 s2 p1, (b,1,256,256) -> fp32 A (b,64,128,128) ========
__global__ void __launch_bounds__(256) enc1_t(
    const float* __restrict__ in, const float* __restrict__ w,
    const float* __restrict__ bias, float* __restrict__ out)
{
  constexpr int OCB = 16;
  int tid = threadIdx.x;
  int rr = tid >> 7, ox = tid & 127;
  int oy  = blockIdx.x * 2 + rr;
  int oc0 = blockIdx.y * OCB;
  int b   = blockIdx.z;

  const float* pl = in + (size_t)b * 65536;
  float v[16];
  #pragma unroll
  for (int ky = 0; ky < 4; ++ky) {
    int iy = 2 * oy - 1 + ky;
    #pragma unroll
    for (int kx = 0; kx < 4; ++kx) {
      int ix = 2 * ox - 1 + kx;
      v[ky * 4 + kx] = (iy >= 0 && iy < 256 && ix >= 0 && ix < 256)
                       ? pl[iy * 256 + ix] : 0.f;
    }
  }
  float acc[OCB];
  #pragma unroll
  for (int o = 0; o < OCB; ++o) acc[o] = bias[oc0 + o];
  #pragma unroll
  for (int t = 0; t < 16; ++t)
    #pragma unroll
    for (int o = 0; o < OCB; ++o)
      acc[o] += v[t] * w[(size_t)(oc0 + o) * 16 + t];

  float* ob = out + ((size_t)b * 64 + oc0) * 16384 + oy * 128 + ox;
  #pragma unroll
  for (int o = 0; o < OCB; ++o)
    ob[(size_t)o * 16384] = fmaxf(acc[o], 0.f);
}

// ======== enc_c2: 4x4 s2 p1, fp32 A -> fp32 B (b,128,64,64), ICB=2 =========
__global__ void __launch_bounds__(256) conv4s2_t(
    const float* __restrict__ in, const float* __restrict__ w,
    const float* __restrict__ bias, float* __restrict__ out)
{
  constexpr int IC = 64, OC = 128, OCB = 16, ICB = 2;
  __shared__ float lds[2][ICB][1300];
  int tid = threadIdx.x;
  int r = tid >> 6, c = tid & 63;
  int ty  = blockIdx.x * 4;
  int oc0 = blockIdx.y * OCB;
  int b   = blockIdx.z;

  const float* inb = in + (size_t)b * IC * 16384;
  float acc[OCB];
  #pragma unroll
  for (int o = 0; o < OCB; ++o) acc[o] = bias[oc0 + o];

  for (int icb = 0; icb < IC / ICB; ++icb) {
    float (*buf)[1300] = lds[icb & 1];
    #pragma unroll
    for (int ii = 0; ii < ICB; ++ii) {
      const float* pl = inb + (size_t)(icb * ICB + ii) * 16384;
      for (int idx = tid; idx < 1300; idx += 256) {
        int rr = idx / 130, cc = idx - rr * 130;
        int iy = ty * 2 + rr - 1, ix = cc - 1;
        float v = 0.f;
        if (iy >= 0 && iy < 128 && ix >= 0 && ix < 128) v = pl[iy * 128 + ix];
        buf[ii][idx] = v;
      }
    }
    __syncthreads();

    #pragma unroll
    for (int ii = 0; ii < ICB; ++ii) {
      int ic = icb * ICB + ii;
      float v[16];
      #pragma unroll
      for (int ky = 0; ky < 4; ++ky)
        #pragma unroll
        for (int kx = 0; kx < 4; ++kx)
          v[ky * 4 + kx] = buf[ii][(2 * r + ky) * 130 + 2 * c + kx];
      #pragma unroll
      for (int t = 0; t < 16; ++t)
        #pragma unroll
        for (int o = 0; o < OCB; ++o)
          acc[o] += v[t] * w[((size_t)(oc0 + o) * IC + ic) * 16 + t];
    }
  }

  float* ob = out + ((size_t)b * OC + oc0) * 4096 + (ty + r) * 64 + c;
  #pragma unroll
  for (int o = 0; o < OCB; ++o)
    ob[(size_t)o * 4096] = fmaxf(acc[o], 0.f);
}

// ======== fp32 3x3 s1 p1 conv at 64x64 (encoder), OCB=16 ===================
template<int IC, int OC, int TR, int OCB, int WMODE, bool BIAS, bool RELU_IN, bool RELU_OUT>
__global__ void __launch_bounds__(TR * 64) conv3_t(
    const float* __restrict__ in, const float* __restrict__ w,
    const float* __restrict__ bias, float* __restrict__ out)
{
  constexpr int ICB = 8;
  constexpr int NE = (TR + 2) * 66;
  __shared__ float lds[2][ICB][NE];
  int tid = threadIdx.x;
  int r = tid >> 6, c = tid & 63;
  int ty  = blockIdx.x * TR;
  int oc0 = blockIdx.y * OCB;
  int b   = blockIdx.z;

  const float* inb = in + (size_t)b * IC * 4096;
  float acc[OCB];
  #pragma unroll
  for (int o = 0; o < OCB; ++o) acc[o] = BIAS ? bias[oc0 + o] : 0.f;

  for (int icb = 0; icb < IC / ICB; ++icb) {
    float (*buf)[NE] = lds[icb & 1];
    #pragma unroll
    for (int ii = 0; ii < ICB; ++ii) {
      const float* pl = inb + (size_t)(icb * ICB + ii) * 4096;
      for (int idx = tid; idx < NE; idx += TR * 64) {
        int rr = idx / 66, cc = idx - rr * 66;
        int iy = ty + rr - 1, ix = cc - 1;
        float v = 0.f;
        if (iy >= 0 && iy < 64 && ix >= 0 && ix < 64) {
          v = pl[iy * 64 + ix];
          if (RELU_IN) v = fmaxf(v, 0.f);
        }
        buf[ii][idx] = v;
      }
    }
    __syncthreads();

    #pragma unroll
    for (int ii = 0; ii < ICB; ++ii) {
      int ic = icb * ICB + ii;
      float v[9];
      #pragma unroll
      for (int ky = 0; ky < 3; ++ky)
        #pragma unroll
        for (int kx = 0; kx < 3; ++kx)
          v[ky * 3 + kx] = buf[ii][(r + ky) * 66 + c + kx];

      #pragma unroll
      for (int t = 0; t < 9; ++t) {
        int ky = t / 3, kx = t - ky * 3;
        #pragma unroll
        for (int o = 0; o < OCB; ++o) {
          float wt = (WMODE == 0)
            ? w[((size_t)(oc0 + o) * IC + ic) * 9 + t]
            : w[((size_t)ic * OC + (oc0 + o)) * 9 + (2 - ky) * 3 + (2 - kx)];
          acc[o] += v[t] * wt;
        }
      }
    }
  }

  float* ob = out + ((size_t)b * OC + oc0) * 4096 + (ty + r) * 64 + c;
  #pragma unroll
  for (int o = 0; o < OCB; ++o) {
    float a = acc[o];
    if (RELU_OUT) a = fmaxf(a, 0.f);
    ob[(size_t)o * 4096] = a;
  }
}

// ======== fp32 res tail: out = relu(x) + w2 @ h (1x1), OCB=8 ===============
__global__ void __launch_bounds__(256) res_add_k(
    const float* __restrict__ x, const float* __restrict__ h,
    const float* __restrict__ w2, float* __restrict__ out)
{
  int p   = blockIdx.x * 256 + threadIdx.x;
  int oc0 = blockIdx.y * 8;
  int b   = blockIdx.z;
  const float* xb = x + ((size_t)b * 128 + oc0) * 4096 + p;
  float acc[8];
  #pragma unroll
  for (int o = 0; o < 8; ++o) acc[o] = fmaxf(xb[(size_t)o * 4096], 0.f);
  const float* hb = h + (size_t)b * 64 * 4096 + p;
  #pragma unroll 4
  for (int ic = 0; ic < 64; ++ic) {
    float v = hb[(size_t)ic * 4096];
    #pragma unroll
    for (int o = 0; o < 8; ++o)
      acc[o] += w2[(oc0 + o) * 64 + ic] * v;
  }
  float* ob = out + ((size_t)b * 128 + oc0) * 4096 + p;
  #pragma unroll
  for (int o = 0; o < 8; ++o) ob[(size_t)o * 4096] = acc[o];
}

// ======== fused pre-VQ 1x1 conv + VQ: fp32 in; qn fp32 + Dq bf16-HWC =======
__global__ void __launch_bounds__(256) vq_k(
    const float* __restrict__ xres, const float* __restrict__ vw,
    const float* __restrict__ vb, const float* __restrict__ emb,
    float* __restrict__ qn, unsigned short* __restrict__ dqb,
    float* __restrict__ sum_sq, int* __restrict__ hist)
{
  int tid = threadIdx.x;
  int n = blockIdx.x * 256 + tid;
  int b = n >> 12;
  int pos = n & 4095;
  int u = pos >> 6, v2 = pos & 63;

  float z[64];
  #pragma unroll
  for (int k = 0; k < 64; ++k) z[k] = vb[k];

  const float* xb = xres + (size_t)b * 128 * 4096 + pos;
  for (int c = 0; c < 128; ++c) {
    float v = fmaxf(xb[(size_t)c * 4096], 0.f);
    #pragma unroll
    for (int k = 0; k < 64; ++k) z[k] += v * vw[k * 128 + c];
  }

  float z2 = 0.f;
  #pragma unroll
  for (int d = 0; d < 64; ++d) z2 += z[d] * z[d];

  float best = INFINITY;
  int bidx = 0;
  for (int k = 0; k < 64; ++k) {
    float dot = 0.f, e2 = 0.f;
    #pragma unroll
    for (int d = 0; d < 64; ++d) {
      float e = emb[k * 64 + d];
      dot += z[d] * e;
      e2  += e * e;
    }
    float dist = z2 + e2 - 2.f * dot;
    if (dist < best) { best = dist; bidx = k; }
  }

  float sq = 0.f;
  const float* eb = emb + bidx * 64;
  float* qb = qn + (size_t)b * 262144 + pos;
  unsigned short* dq = dqb + (size_t)b * 278784 + ((size_t)(u + 1) * 66 + (v2 + 1)) * 64;
  #pragma unroll
  for (int d = 0; d < 64; ++d) {
    float e = eb[d];
    float df = e - z[d];
    sq += df * df;
    qb[(size_t)d * 4096] = e;
    dq[d] = f2bf(e);
  }

  __shared__ float red[256];
  __shared__ int lh[64];
  red[tid] = sq;
  if (tid < 64) lh[tid] = 0;
  __syncthreads();
  atomicAdd(&lh[bidx], 1);
  for (int s = 128; s > 0; s >>= 1) {
    if (tid < s) red[tid] += red[tid + s];
    __syncthreads();
  }
  if (tid == 0) atomicAdd(sum_sq, red[0]);
  if (tid < 64) atomicAdd(&hist[tid], lh[tid]);
}

// ======== bf16 MFMA tap-GEMM conv (decoder) ================================
template<int IC, int OC, int MODE, bool HAS_BIAS, bool HAS_SKIP, bool RELU>
__global__ void __launch_bounds__(256) mfma_conv(
    const unsigned short* __restrict__ in, const unsigned short* __restrict__ wt,
    const float* __restrict__ bias, const unsigned short* __restrict__ skip,
    unsigned short* __restrict__ out, int ry, int rx, int in_ss, int out_ss)
{
  constexpr int OM = OC / 16;
  constexpr int NT = (MODE == 0) ? 9 : ((MODE == 1) ? 4 : 1);
  const int tid = threadIdx.x;
  const int wv = tid >> 6, lane = tid & 63;
  const int quad = lane >> 4, l15 = lane & 15;
  const int b = blockIdx.z;
  const int y0 = blockIdx.x * 2;
  const int t0 = wv * 2, t1 = t0 + 1;
  const int yA = y0 + (t0 >> 2), xA = ((t0 & 3) << 4) + l15;
  const int yB = y0 + (t1 >> 2), xB = ((t1 & 3) << 4) + l15;
  const unsigned short* inb = in + (size_t)b * (size_t)in_ss;

  f32x4 acc[OM][2];
  #pragma unroll
  for (int m = 0; m < OM; ++m) {
    const int oc0 = m * 16 + quad * 4;
    f32x4 ini0 = {0.f, 0.f, 0.f, 0.f};
    if (HAS_BIAS) {
      float4 bs = *(const float4*)(bias + oc0);
      ini0[0] = bs.x; ini0[1] = bs.y; ini0[2] = bs.z; ini0[3] = bs.w;
    }
    f32x4 ini1 = ini0;
    if (HAS_SKIP) {
      const unsigned short* s0 = skip + (size_t)b * (size_t)out_ss
                               + ((size_t)(yA + 1) * 66 + (xA + 1)) * OC + oc0;
      const unsigned short* s1 = skip + (size_t)b * (size_t)out_ss
                               + ((size_t)(yB + 1) * 66 + (xB + 1)) * OC + oc0;
      #pragma unroll
      for (int r = 0; r < 4; ++r) { ini0[r] += bf2f(s0[r]); ini1[r] += bf2f(s1[r]); }
    }
    acc[m][0] = ini0; acc[m][1] = ini1;
  }

  #pragma unroll
  for (int t = 0; t < NT; ++t) {
    const int dy = (MODE == 0) ? (t / 3 - 1) : ((MODE == 1) ? (ry - (t >> 1)) : 0);
    const int dx = (MODE == 0) ? (t % 3 - 1) : ((MODE == 1) ? (rx - (t & 1)) : 0);
    const unsigned short* rA = inb + ((size_t)(yA + dy + 1) * 66 + (xA + dx + 1)) * IC + quad * 8;
    const unsigned short* rB = inb + ((size_t)(yB + dy + 1) * 66 + (xB + dx + 1)) * IC + quad * 8;
    const unsigned short* wr = wt + (size_t)t * OC * IC + (size_t)l15 * IC + quad * 8;
    #pragma unroll
    for (int k0 = 0; k0 < IC; k0 += 32) {
      short8 fb0 = *(const short8*)(rA + k0);
      short8 fb1 = *(const short8*)(rB + k0);
      #pragma unroll
      for (int m = 0; m < OM; ++m) {
        short8 fa = *(const short8*)(wr + (size_t)m * 16 * IC + k0);
        acc[m][0] = __builtin_amdgcn_mfma_f32_16x16x32_bf16(fa, fb0, acc[m][0], 0, 0, 0);
        acc[m][1] = __builtin_amdgcn_mfma_f32_16x16x32_bf16(fa, fb1, acc[m][1], 0, 0, 0);
      }
    }
  }

  #pragma unroll
  for (int m = 0; m < OM; ++m) {
    const int oc0 = m * 16 + quad * 4;
    unsigned short* o0 = out + (size_t)b * (size_t)out_ss
                       + ((size_t)(yA + 1) * 66 + (xA + 1)) * OC + oc0;
    unsigned short* o1 = out + (size_t)b * (size_t)out_ss
                       + ((size_t)(yB + 1) * 66 + (xB + 1)) * OC + oc0;
    ushort4 u0, u1;
    float v;
    v = acc[m][0][0]; if (RELU) v = fmaxf(v, 0.f); u0.x = f2bf(v);
    v = acc[m][0][1]; if (RELU) v = fmaxf(v, 0.f); u0.y = f2bf(v);
    v = acc[m][0][2]; if (RELU) v = fmaxf(v, 0.f); u0.z = f2bf(v);
    v = acc[m][0][3]; if (RELU) v = fmaxf(v, 0.f); u0.w = f2bf(v);
    v = acc[m][1][0]; if (RELU) v = fmaxf(v, 0.f); u1.x = f2bf(v);
    v = acc[m][1][1]; if (RELU) v = fmaxf(v, 0.f); u1.y = f2bf(v);
    v = acc[m][1][2]; if (RELU) v = fmaxf(v, 0.f); u1.z = f2bf(v);
    v = acc[m][1][3]; if (RELU) v = fmaxf(v, 0.f); u1.w = f2bf(v);
    *(ushort4*)o0 = u0;
    *(ushort4*)o1 = u1;
  }
}

// ======== dec_c3: LDS-free, short8 channel-octet loads =====================
// Thread (y,x) in 128-grid computes the 2x2 output block. 9 base pointers
// hoisted; per octet: 9 x 16B loads, 128 FMA. Fixes round-6 60x over-fetch.
__global__ void __launch_bounds__(256) dec3_t(
    const unsigned short* __restrict__ p4, const float* __restrict__ w,
    const float* __restrict__ bias, float* __restrict__ out)
{
  int tid = threadIdx.x;
  int yr = tid >> 7, x = tid & 127;
  int y  = blockIdx.x * 2 + yr;
  int b  = blockIdx.z;

  const int kt[2][2] = {{1, 3}, {0, 2}};
  const int dt[2][2] = {{1, 0}, {2, 1}};

  const unsigned short* base[9];
  #pragma unroll
  for (int dy = 0; dy < 3; ++dy) {
    int iy = y + dy - 1;
    int py = iy & 1, u = iy >> 1;          // arithmetic shift: -1 -> pad row
    #pragma unroll
    for (int dx = 0; dx < 3; ++dx) {
      int ix = x + dx - 1;
      int px = ix & 1, v = ix >> 1;
      base[dy * 3 + dx] = p4 + ((size_t)(b * 4 + py * 2 + px) * 4356
                                + (size_t)(u + 1) * 66 + (v + 1)) * 64;
    }
  }

  float acc[4] = {0.f, 0.f, 0.f, 0.f};
  for (int oct = 0; oct < 8; ++oct) {
    ushort8 s[9];
    #pragma unroll
    for (int t = 0; t < 9; ++t)
      s[t] = *(const ushort8*)(base[t] + oct * 8);

    #pragma unroll
    for (int j = 0; j < 8; ++j) {
      const float* wp = w + (size_t)(oct * 8 + j) * 16;
      float v9[9];
      #pragma unroll
      for (int t = 0; t < 9; ++t) v9[t] = bf2f(s[t][j]);
      #pragma unroll
      for (int ry = 0; ry < 2; ++ry)
        #pragma unroll
        for (int rx = 0; rx < 2; ++rx)
          #pragma unroll
          for (int a = 0; a < 2; ++a)
            #pragma unroll
            for (int c2 = 0; c2 < 2; ++c2)
              acc[ry * 2 + rx] += v9[dt[ry][a] * 3 + dt[rx][c2]]
                                * wp[kt[ry][a] * 4 + kt[rx][c2]];
    }
  }

  float b0 = bias[0];
  float* ob = out + (size_t)b * 65536;
  #pragma unroll
  for (int ry = 0; ry < 2; ++ry)
    #pragma unroll
    for (int rx = 0; rx < 2; ++rx)
      ob[(2 * y + ry) * 256 + 2 * x + rx] = tanhf(acc[ry * 2 + rx] + b0);
}

// ======== aux: zero the pad ring of a padded-HWC bf16 buffer ===============
__global__ void ring_zero_k(unsigned short* __restrict__ buf, int ic, int icl)
{
  unsigned short* p = buf + (size_t)blockIdx.x * 4356 * ic;
  int total = 260 * ic;
  for (int idx = threadIdx.x; idx < total; idx += 256) {
    int cell = idx >> icl;
    int e = idx & (ic - 1);
    int row, col;
    if (cell < 66)       { row = 0;  col = cell; }
    else if (cell < 132) { row = 65; col = cell - 66; }
    else if (cell < 196) { row = cell - 132 + 1; col = 0; }
    else                 { row = cell - 196 + 1; col = 65; }
    p[(size_t)(row * 66 + col) * ic + e] = 0;
  }
}

// ======== aux: repack decoder weights to bf16 [tap][oc][ic] ================
__global__ void repack_k(const float* __restrict__ c1w, const float* __restrict__ r1w,
                         const float* __restrict__ r2w, const float* __restrict__ c2w,
                         unsigned short* __restrict__ W)
{
  int idx = blockIdx.x * 256 + threadIdx.x;
  if (idx >= 286720) return;
  float val;
  if (idx < 73728) {                       // dec_c1: transposed 3x3, flipped
    int t = idx / 8192, rem = idx & 8191;
    int oc = rem >> 6, ic = rem & 63;
    int ky = t / 3, kx = t - ky * 3;
    val = c1w[((ic * 128 + oc) * 3 + (2 - ky)) * 3 + (2 - kx)];
  } else if (idx < 147456) {               // r1: OIHW direct
    int j = idx - 73728;
    int t = j / 8192, rem = j & 8191;
    int oc = rem >> 7, ic = rem & 127;
    int ky = t / 3, kx = t - ky * 3;
    val = r1w[((oc * 128 + ic) * 3 + ky) * 3 + kx];
  } else if (idx < 155648) {               // r2: 1x1 OIHW
    int j = idx - 147456;
    int oc = j >> 6, ic = j & 63;
    val = r2w[oc * 64 + ic];
  } else {                                 // dec2 parity: w (Cin=128,Cout=64,4,4)
    int j = idx - 155648;
    int p = j >> 15;
    int t2 = (j >> 13) & 3;
    int oc = (j >> 7) & 63;
    int ic = j & 127;
    int ry = p >> 1, rx = p & 1;
    int aY = t2 >> 1, aX = t2 & 1;
    int ky = aY ? (3 - ry) : (1 - ry);
    int kx = aX ? (3 - rx) : (1 - rx);
    val = c2w[((ic * 64 + oc) * 4 + ky) * 4 + kx];
  }
  W[idx] = f2bf(val);
}

// ======== scratch init + scalar finalize ===================================
__global__ void init_k(float* sum_sq, int* hist)
{
  int t = threadIdx.x;
  if (t == 0) sum_sq[0] = 0.f;
  if (t < 64) hist[t] = 0;
}

__global__ void finalize_k(const float* __restrict__ sum_sq, const int* __restrict__ hist,
                           float* __restrict__ loss_out, float* __restrict__ perp_out)
{
  if (threadIdx.x == 0) {
    float mse = sum_sq[0] / (float)NELEM;
    loss_out[0] = 1.25f * mse;
    float ent = 0.f;
    for (int k = 0; k < 64; ++k) {
      float p = (float)hist[k] / (float)NPOS;
      ent += p * logf(p + 1e-10f);
    }
    perp_out[0] = expf(-ent);
  }
}

// ---------------------------------------------------------------------------
extern "C" void kernel_launch(void* const* d_in, const int* in_sizes, int n_in,
                              void* d_out, int out_size, void* d_ws, size_t ws_size,
                              hipStream_t stream)
{
  const float* x        = (const float*)d_in[0];
  const float* enc_c1_w = (const float*)d_in[1];
  const float* enc_c1_b = (const float*)d_in[2];
  const float* enc_c2_w = (const float*)d_in[3];
  const float* enc_c2_b = (const float*)d_in[4];
  const float* enc_c3_w = (const float*)d_in[5];
  const float* enc_c3_b = (const float*)d_in[6];
  const float* enc_r1_w = (const float*)d_in[7];
  const float* enc_r2_w = (const float*)d_in[8];
  const float* vqc_w    = (const float*)d_in[9];
  const float* vqc_b    = (const float*)d_in[10];
  const float* emb      = (const float*)d_in[11];
  const float* dec_c1_w = (const float*)d_in[12];
  const float* dec_c1_b = (const float*)d_in[13];
  const float* dec_r1_w = (const float*)d_in[14];
  const float* dec_r2_w = (const float*)d_in[15];
  const float* dec_c2_w = (const float*)d_in[16];
  const float* dec_c2_b = (const float*)d_in[17];
  const float* dec_c3_w = (const float*)d_in[18];
  const float* dec_c3_b = (const float*)d_in[19];

  float* out      = (float*)d_out;
  float* loss_out = out;
  float* xre_out  = out + 1;
  float* perp_out = out + 1 + 2097152;
  float* qn_out   = out + 2 + 2097152;

  float* sum_sq = (float*)d_ws;
  int*   hist   = (int*)d_ws + 1;
  char*  pool   = (char*)d_ws + 1024;

  float*          A  = (float*)(pool + 0);
  float*          B  = (float*)(pool + 134217728);
  float*          C  = (float*)(pool + 0);
  float*          D  = (float*)(pool + 201326592);
  unsigned short* Dq = (unsigned short*)(pool + 67108864);
  unsigned short* Y1 = (unsigned short*)(pool + 134217728);
  unsigned short* S  = (unsigned short*)(pool + 170000000);
  unsigned short* Y2 = (unsigned short*)(pool + 90000000);
  unsigned short* P4 = (unsigned short*)(pool + 0);
  unsigned short* W  = (unsigned short*)(pool + 240000000);

  const int SS64  = 278784;
  const int SS128 = 557568;
  const int SSP4  = 1115136;

  hipLaunchKernelGGL(init_k, dim3(1), dim3(128), 0, stream, sum_sq, hist);
  hipLaunchKernelGGL(repack_k, dim3(1120), dim3(256), 0, stream,
                     dec_c1_w, dec_r1_w, dec_r2_w, dec_c2_w, W);

  // ---- encoder (fp32, protects VQ precision) ----
  hipLaunchKernelGGL(enc1_t, dim3(64, 4, 32), dim3(256), 0, stream,
                     x, enc_c1_w, enc_c1_b, A);
  hipLaunchKernelGGL(conv4s2_t, dim3(16, 8, 32), dim3(256), 0, stream,
                     A, enc_c2_w, enc_c2_b, B);
  hipLaunchKernelGGL((conv3_t<128, 128, 4, 16, 0, true, false, false>),
                     dim3(16, 8, 32), dim3(256), 0, stream,
                     B, enc_c3_w, enc_c3_b, C);
  hipLaunchKernelGGL((conv3_t<128, 64, 4, 16, 0, false, true, true>),
                     dim3(16, 4, 32), dim3(256), 0, stream,
                     C, enc_r1_w, nullptr, D);
  hipLaunchKernelGGL(res_add_k, dim3(16, 16, 32), dim3(256), 0, stream,
                     C, D, enc_r2_w, B);
  hipLaunchKernelGGL((conv3_t<128, 64, 4, 16, 0, false, true, true>),
                     dim3(16, 4, 32), dim3(256), 0, stream,
                     B, enc_r1_w, nullptr, D);
  hipLaunchKernelGGL(res_add_k, dim3(16, 16, 32), dim3(256), 0, stream,
                     B, D, enc_r2_w, C);

  // ---- VQ: qn fp32 out + bf16 padded-HWC q for decoder ----
  hipLaunchKernelGGL(vq_k, dim3(512), dim3(256), 0, stream,
                     C, vqc_w, vqc_b, emb, qn_out, Dq, sum_sq, hist);

  hipLaunchKernelGGL(ring_zero_k, dim3(32), dim3(256), 0, stream, Dq, 64, 6);
  hipLaunchKernelGGL(ring_zero_k, dim3(32), dim3(256), 0, stream, Y1, 128, 7);
  hipLaunchKernelGGL(ring_zero_k, dim3(32), dim3(256), 0, stream, Y2, 128, 7);
  hipLaunchKernelGGL(ring_zero_k, dim3(32), dim3(256), 0, stream, S, 64, 6);

  // ---- decoder (bf16 MFMA) ----
  hipLaunchKernelGGL((mfma_conv<64, 128, 0, true, false, true>),
                     dim3(32, 1, 32), dim3(256), 0, stream,
                     Dq, W, dec_c1_b, nullptr, Y1, 0, 0, SS64, SS128);
  hipLaunchKernelGGL((mfma_conv<128, 64, 0, false, false, true>),
                     dim3(32, 1, 32), dim3(256), 0, stream,
                     Y1, W + 73728, nullptr, nullptr, S, 0, 0, SS128, SS64);
  hipLaunchKernelGGL((mfma_conv<64, 128, 2, false, true, true>),
                     dim3(32, 1, 32), dim3(256), 0, stream,
                     S, W + 147456, nullptr, Y1, Y2, 0, 0, SS64, SS128);
  hipLaunchKernelGGL((mfma_conv<128, 64, 0, false, false, true>),
                     dim3(32, 1, 32), dim3(256), 0, stream,
                     Y2, W + 73728, nullptr, nullptr, S, 0, 0, SS128, SS64);
  hipLaunchKernelGGL((mfma_conv<64, 128, 2, false, true, true>),
                     dim3(32, 1, 32), dim3(256), 0, stream,
                     S, W + 147456, nullptr, Y2, Y1, 0, 0, SS64, SS128);

  hipLaunchKernelGGL(ring_zero_k, dim3(128), dim3(256), 0, stream, P4, 64, 6);

  for (int p = 0; p < 4; ++p) {
    hipLaunchKernelGGL((mfma_conv<128, 64, 1, true, false, true>),
                       dim3(32, 1, 32), dim3(256), 0, stream,
                       Y1, W + 155648 + p * 32768, dec_c2_b, nullptr,
                       P4 + (size_t)p * 4356 * 64, p >> 1, p & 1, SS128, SSP4);
  }

  hipLaunchKernelGGL(dec3_t, dim3(64, 1, 32), dim3(256), 0, stream,
                     P4, dec_c3_w, dec_c3_b, xre_out);

  hipLaunchKernelGGL(finalize_k, dim3(1), dim3(64), 0, stream,
                     sum_sq, hist, loss_out, perp_out);
}

// Round 8
// 2512.548 us; speedup vs baseline: 4.2840x; 1.6792x over previous
//
#include <hip/hip_runtime.h>
#include <cmath>

// ---------------------------------------------------------------------------
// VQ-VAE forward, round 8.
// Round-7: fp32 encoder was the wall (conv3_t 1.15ms @ 49% VALUBusy, ~33 TF;
// fp32 vector ceiling 157 TF). This round: encoder on MFMA via split-bf16
// (bf16x3): a = a_hi + a_lo, a*b ~= ah*bh + ah*bl + al*bh, fp32 accum =>
// ~1e-6 rel error (VQ argmin safe; straight bf16 would flip too many).
// All encoder activations: padded-HWC bf16 hi/lo pairs, post-relu storage
// (res chain only consumes relu(x)). enc_c2 = 16-tap stride-2 tap-GEMM.
// vq reads hi/lo HWC contiguously. Decoder unchanged (validated r6/r7).
// Pool liveness: peak ~231 MB < proven 264 MB ws.
// ---------------------------------------------------------------------------

static constexpr int NPOS  = 131072;
static constexpr long long NELEM = 8388608;

typedef __attribute__((ext_vector_type(8))) short short8;
typedef __attribute__((ext_vector_type(8))) unsigned short ushort8;
typedef __attribute__((ext_vector_type(4))) float f32x4;

__device__ __forceinline__ unsigned short f2bf(float f) {
  unsigned int x = __float_as_uint(f);
  unsigned int r = (x + 0x7fffu + ((x >> 16) & 1u)) >> 16;
  return (unsigned short)r;
}
__device__ __forceinline__ float bf2f(unsigned short u) {
  return __uint_as_float(((unsigned int)u) << 16);
}
__device__ __forceinline__ void split2(float v, unsigned short& h, unsigned short& l) {
  unsigned short hh = f2bf(v);
  h = hh;
  l = f2bf(v - bf2f(hh));
}

// ======== enc_c1: 4x4 s2 p1, (b,1,256,256) -> hi/lo HWC (130x130x64) =======
__global__ void __launch_bounds__(256) enc1_t(
    const float* __restrict__ in, const float* __restrict__ w,
    const float* __restrict__ bias,
    unsigned short* __restrict__ outh, unsigned short* __restrict__ outl)
{
  int tid = threadIdx.x;
  int rr = tid >> 7, ox = tid & 127;
  int oy  = blockIdx.x * 2 + rr;
  int oc0 = blockIdx.y * 16;
  int b   = blockIdx.z;

  const float* pl = in + (size_t)b * 65536;
  float v[16];
  #pragma unroll
  for (int ky = 0; ky < 4; ++ky) {
    int iy = 2 * oy - 1 + ky;
    #pragma unroll
    for (int kx = 0; kx < 4; ++kx) {
      int ix = 2 * ox - 1 + kx;
      v[ky * 4 + kx] = (iy >= 0 && iy < 256 && ix >= 0 && ix < 256)
                       ? pl[iy * 256 + ix] : 0.f;
    }
  }
  float acc[16];
  #pragma unroll
  for (int o = 0; o < 16; ++o) acc[o] = bias[oc0 + o];
  #pragma unroll
  for (int t = 0; t < 16; ++t)
    #pragma unroll
    for (int o = 0; o < 16; ++o)
      acc[o] += v[t] * w[(size_t)(oc0 + o) * 16 + t];

  size_t o = ((size_t)b * 16900 + (size_t)(oy + 1) * 130 + (ox + 1)) * 64 + oc0;
  ushort8 h0, h1, l0, l1;
  #pragma unroll
  for (int k = 0; k < 8; ++k) {
    unsigned short hh, ll;
    split2(fmaxf(acc[k], 0.f), hh, ll);      h0[k] = hh; l0[k] = ll;
    split2(fmaxf(acc[k + 8], 0.f), hh, ll);  h1[k] = hh; l1[k] = ll;
  }
  *(ushort8*)(outh + o)     = h0;
  *(ushort8*)(outh + o + 8) = h1;
  *(ushort8*)(outl + o)     = l0;
  *(ushort8*)(outl + o + 8) = l1;
}

// ======== bf16x3 MFMA tap-GEMM (encoder) ===================================
// MODE 0: 3x3 s1 (66-pad in). MODE 1: 4x4 s2 (130-pad in). MODE 2: 1x1+skip.
// in/out padded HWC hi/lo. w: [tap][oc][ic] hi/lo. out 66x66xOC hi/lo.
template<int IC, int OC, int MODE, bool BIAS, bool RELU>
__global__ void __launch_bounds__(256) mfma_enc(
    const unsigned short* __restrict__ inh, const unsigned short* __restrict__ inl,
    const unsigned short* __restrict__ wh, const unsigned short* __restrict__ wl,
    const float* __restrict__ bias,
    const unsigned short* __restrict__ skh, const unsigned short* __restrict__ skl,
    unsigned short* __restrict__ outh, unsigned short* __restrict__ outl)
{
  constexpr int OM = OC / 16;
  constexpr int NT = (MODE == 0) ? 9 : ((MODE == 1) ? 16 : 1);
  constexpr int IW = (MODE == 1) ? 130 : 66;
  const int in_ss  = IW * IW * IC;
  const int out_ss = 4356 * OC;
  const int tid = threadIdx.x;
  const int wv = tid >> 6, lane = tid & 63;
  const int quad = lane >> 4, l15 = lane & 15;
  const int b = blockIdx.z;
  const int y0 = blockIdx.x * 2;
  const int t0 = wv * 2, t1 = t0 + 1;
  const int yA = y0 + (t0 >> 2), xA = ((t0 & 3) << 4) + l15;
  const int yB = y0 + (t1 >> 2), xB = ((t1 & 3) << 4) + l15;
  const unsigned short* ibh = inh + (size_t)b * in_ss;
  const unsigned short* ibl = inl + (size_t)b * in_ss;

  f32x4 acc[OM][2];
  #pragma unroll
  for (int m = 0; m < OM; ++m) {
    const int oc0 = m * 16 + quad * 4;
    f32x4 i0 = {0.f, 0.f, 0.f, 0.f};
    if (BIAS) {
      float4 bs = *(const float4*)(bias + oc0);
      i0[0] = bs.x; i0[1] = bs.y; i0[2] = bs.z; i0[3] = bs.w;
    }
    f32x4 i1 = i0;
    if (MODE == 2) {
      size_t s0 = (size_t)b * out_ss + ((size_t)(yA + 1) * 66 + (xA + 1)) * OC + oc0;
      size_t s1 = (size_t)b * out_ss + ((size_t)(yB + 1) * 66 + (xB + 1)) * OC + oc0;
      #pragma unroll
      for (int r = 0; r < 4; ++r) {
        i0[r] += bf2f(skh[s0 + r]) + bf2f(skl[s0 + r]);
        i1[r] += bf2f(skh[s1 + r]) + bf2f(skl[s1 + r]);
      }
    }
    acc[m][0] = i0; acc[m][1] = i1;
  }

  for (int t = 0; t < NT; ++t) {
    int offA, offB;
    if (MODE == 1) {
      offA = ((2 * yA + (t >> 2)) * 130 + (2 * xA + (t & 3))) * IC;
      offB = ((2 * yB + (t >> 2)) * 130 + (2 * xB + (t & 3))) * IC;
    } else if (MODE == 0) {
      int dy = t / 3 - 1, dx = t % 3 - 1;
      offA = ((yA + dy + 1) * 66 + (xA + dx + 1)) * IC;
      offB = ((yB + dy + 1) * 66 + (xB + dx + 1)) * IC;
    } else {
      offA = ((yA + 1) * 66 + (xA + 1)) * IC;
      offB = ((yB + 1) * 66 + (xB + 1)) * IC;
    }
    const unsigned short* wrh = wh + (size_t)t * OC * IC + l15 * IC + quad * 8;
    const unsigned short* wrl = wl + (size_t)t * OC * IC + l15 * IC + quad * 8;
    #pragma unroll
    for (int k0 = 0; k0 < IC; k0 += 32) {
      short8 b0h = *(const short8*)(ibh + offA + quad * 8 + k0);
      short8 b0l = *(const short8*)(ibl + offA + quad * 8 + k0);
      short8 b1h = *(const short8*)(ibh + offB + quad * 8 + k0);
      short8 b1l = *(const short8*)(ibl + offB + quad * 8 + k0);
      #pragma unroll
      for (int m = 0; m < OM; ++m) {
        short8 ah = *(const short8*)(wrh + (size_t)m * 16 * IC + k0);
        short8 al = *(const short8*)(wrl + (size_t)m * 16 * IC + k0);
        acc[m][0] = __builtin_amdgcn_mfma_f32_16x16x32_bf16(ah, b0h, acc[m][0], 0, 0, 0);
        acc[m][0] = __builtin_amdgcn_mfma_f32_16x16x32_bf16(ah, b0l, acc[m][0], 0, 0, 0);
        acc[m][0] = __builtin_amdgcn_mfma_f32_16x16x32_bf16(al, b0h, acc[m][0], 0, 0, 0);
        acc[m][1] = __builtin_amdgcn_mfma_f32_16x16x32_bf16(ah, b1h, acc[m][1], 0, 0, 0);
        acc[m][1] = __builtin_amdgcn_mfma_f32_16x16x32_bf16(ah, b1l, acc[m][1], 0, 0, 0);
        acc[m][1] = __builtin_amdgcn_mfma_f32_16x16x32_bf16(al, b1h, acc[m][1], 0, 0, 0);
      }
    }
  }

  #pragma unroll
  for (int m = 0; m < OM; ++m) {
    const int oc0 = m * 16 + quad * 4;
    size_t o0 = (size_t)b * out_ss + ((size_t)(yA + 1) * 66 + (xA + 1)) * OC + oc0;
    size_t o1 = (size_t)b * out_ss + ((size_t)(yB + 1) * 66 + (xB + 1)) * OC + oc0;
    ushort4 h0, l0, h1, l1;
    unsigned short hh, ll;
    float v;
    v = acc[m][0][0]; if (RELU) v = fmaxf(v, 0.f); split2(v, hh, ll); h0.x = hh; l0.x = ll;
    v = acc[m][0][1]; if (RELU) v = fmaxf(v, 0.f); split2(v, hh, ll); h0.y = hh; l0.y = ll;
    v = acc[m][0][2]; if (RELU) v = fmaxf(v, 0.f); split2(v, hh, ll); h0.z = hh; l0.z = ll;
    v = acc[m][0][3]; if (RELU) v = fmaxf(v, 0.f); split2(v, hh, ll); h0.w = hh; l0.w = ll;
    v = acc[m][1][0]; if (RELU) v = fmaxf(v, 0.f); split2(v, hh, ll); h1.x = hh; l1.x = ll;
    v = acc[m][1][1]; if (RELU) v = fmaxf(v, 0.f); split2(v, hh, ll); h1.y = hh; l1.y = ll;
    v = acc[m][1][2]; if (RELU) v = fmaxf(v, 0.f); split2(v, hh, ll); h1.z = hh; l1.z = ll;
    v = acc[m][1][3]; if (RELU) v = fmaxf(v, 0.f); split2(v, hh, ll); h1.w = hh; l1.w = ll;
    *(ushort4*)(outh + o0) = h0; *(ushort4*)(outl + o0) = l0;
    *(ushort4*)(outh + o1) = h1; *(ushort4*)(outl + o1) = l1;
  }
}

// ======== fused pre-VQ 1x1 conv + VQ: hi/lo HWC in; qn fp32 + Dq bf16 ======
__global__ void __launch_bounds__(256, 2) vq_k(
    const unsigned short* __restrict__ xh, const unsigned short* __restrict__ xl,
    const float* __restrict__ vw, const float* __restrict__ vb,
    const float* __restrict__ emb,
    float* __restrict__ qn, unsigned short* __restrict__ dqb,
    float* __restrict__ sum_sq, int* __restrict__ hist)
{
  int tid = threadIdx.x;
  int n = blockIdx.x * 256 + tid;
  int b = n >> 12;
  int pos = n & 4095;
  int u = pos >> 6, v2 = pos & 63;

  float z[64];
  #pragma unroll
  for (int k = 0; k < 64; ++k) z[k] = vb[k];

  size_t ibase = ((size_t)b * 4356 + (size_t)(u + 1) * 66 + (v2 + 1)) * 128;
  for (int c0 = 0; c0 < 128; c0 += 8) {
    ushort8 hh = *(const ushort8*)(xh + ibase + c0);
    ushort8 ll = *(const ushort8*)(xl + ibase + c0);
    #pragma unroll
    for (int j = 0; j < 8; ++j) {
      float v = bf2f(hh[j]) + bf2f(ll[j]);
      #pragma unroll
      for (int k = 0; k < 64; ++k) z[k] += v * vw[k * 128 + c0 + j];
    }
  }

  float z2 = 0.f;
  #pragma unroll
  for (int d = 0; d < 64; ++d) z2 += z[d] * z[d];

  float best = INFINITY;
  int bidx = 0;
  for (int k = 0; k < 64; ++k) {
    float dot = 0.f, e2 = 0.f;
    #pragma unroll
    for (int d = 0; d < 64; ++d) {
      float e = emb[k * 64 + d];
      dot += z[d] * e;
      e2  += e * e;
    }
    float dist = z2 + e2 - 2.f * dot;
    if (dist < best) { best = dist; bidx = k; }
  }

  float sq = 0.f;
  const float* eb = emb + bidx * 64;
  float* qb = qn + (size_t)b * 262144 + pos;
  unsigned short* dq = dqb + (size_t)b * 278784 + ((size_t)(u + 1) * 66 + (v2 + 1)) * 64;
  #pragma unroll
  for (int d = 0; d < 64; ++d) {
    float e = eb[d];
    float df = e - z[d];
    sq += df * df;
    qb[(size_t)d * 4096] = e;
    dq[d] = f2bf(e);
  }

  __shared__ float red[256];
  __shared__ int lh[64];
  red[tid] = sq;
  if (tid < 64) lh[tid] = 0;
  __syncthreads();
  atomicAdd(&lh[bidx], 1);
  for (int s = 128; s > 0; s >>= 1) {
    if (tid < s) red[tid] += red[tid + s];
    __syncthreads();
  }
  if (tid == 0) atomicAdd(sum_sq, red[0]);
  if (tid < 64) atomicAdd(&hist[tid], lh[tid]);
}

// ======== bf16 MFMA tap-GEMM (decoder, unchanged from r6/r7) ===============
template<int IC, int OC, int MODE, bool HAS_BIAS, bool HAS_SKIP, bool RELU>
__global__ void __launch_bounds__(256) mfma_conv(
    const unsigned short* __restrict__ in, const unsigned short* __restrict__ wt,
    const float* __restrict__ bias, const unsigned short* __restrict__ skip,
    unsigned short* __restrict__ out, int ry, int rx, int in_ss, int out_ss)
{
  constexpr int OM = OC / 16;
  constexpr int NT = (MODE == 0) ? 9 : ((MODE == 1) ? 4 : 1);
  const int tid = threadIdx.x;
  const int wv = tid >> 6, lane = tid & 63;
  const int quad = lane >> 4, l15 = lane & 15;
  const int b = blockIdx.z;
  const int y0 = blockIdx.x * 2;
  const int t0 = wv * 2, t1 = t0 + 1;
  const int yA = y0 + (t0 >> 2), xA = ((t0 & 3) << 4) + l15;
  const int yB = y0 + (t1 >> 2), xB = ((t1 & 3) << 4) + l15;
  const unsigned short* inb = in + (size_t)b * (size_t)in_ss;

  f32x4 acc[OM][2];
  #pragma unroll
  for (int m = 0; m < OM; ++m) {
    const int oc0 = m * 16 + quad * 4;
    f32x4 ini0 = {0.f, 0.f, 0.f, 0.f};
    if (HAS_BIAS) {
      float4 bs = *(const float4*)(bias + oc0);
      ini0[0] = bs.x; ini0[1] = bs.y; ini0[2] = bs.z; ini0[3] = bs.w;
    }
    f32x4 ini1 = ini0;
    if (HAS_SKIP) {
      const unsigned short* s0 = skip + (size_t)b * (size_t)out_ss
                               + ((size_t)(yA + 1) * 66 + (xA + 1)) * OC + oc0;
      const unsigned short* s1 = skip + (size_t)b * (size_t)out_ss
                               + ((size_t)(yB + 1) * 66 + (xB + 1)) * OC + oc0;
      #pragma unroll
      for (int r = 0; r < 4; ++r) { ini0[r] += bf2f(s0[r]); ini1[r] += bf2f(s1[r]); }
    }
    acc[m][0] = ini0; acc[m][1] = ini1;
  }

  #pragma unroll
  for (int t = 0; t < NT; ++t) {
    const int dy = (MODE == 0) ? (t / 3 - 1) : ((MODE == 1) ? (ry - (t >> 1)) : 0);
    const int dx = (MODE == 0) ? (t % 3 - 1) : ((MODE == 1) ? (rx - (t & 1)) : 0);
    const unsigned short* rA = inb + ((size_t)(yA + dy + 1) * 66 + (xA + dx + 1)) * IC + quad * 8;
    const unsigned short* rB = inb + ((size_t)(yB + dy + 1) * 66 + (xB + dx + 1)) * IC + quad * 8;
    const unsigned short* wr = wt + (size_t)t * OC * IC + (size_t)l15 * IC + quad * 8;
    #pragma unroll
    for (int k0 = 0; k0 < IC; k0 += 32) {
      short8 fb0 = *(const short8*)(rA + k0);
      short8 fb1 = *(const short8*)(rB + k0);
      #pragma unroll
      for (int m = 0; m < OM; ++m) {
        short8 fa = *(const short8*)(wr + (size_t)m * 16 * IC + k0);
        acc[m][0] = __builtin_amdgcn_mfma_f32_16x16x32_bf16(fa, fb0, acc[m][0], 0, 0, 0);
        acc[m][1] = __builtin_amdgcn_mfma_f32_16x16x32_bf16(fa, fb1, acc[m][1], 0, 0, 0);
      }
    }
  }

  #pragma unroll
  for (int m = 0; m < OM; ++m) {
    const int oc0 = m * 16 + quad * 4;
    unsigned short* o0 = out + (size_t)b * (size_t)out_ss
                       + ((size_t)(yA + 1) * 66 + (xA + 1)) * OC + oc0;
    unsigned short* o1 = out + (size_t)b * (size_t)out_ss
                       + ((size_t)(yB + 1) * 66 + (xB + 1)) * OC + oc0;
    ushort4 u0, u1;
    float v;
    v = acc[m][0][0]; if (RELU) v = fmaxf(v, 0.f); u0.x = f2bf(v);
    v = acc[m][0][1]; if (RELU) v = fmaxf(v, 0.f); u0.y = f2bf(v);
    v = acc[m][0][2]; if (RELU) v = fmaxf(v, 0.f); u0.z = f2bf(v);
    v = acc[m][0][3]; if (RELU) v = fmaxf(v, 0.f); u0.w = f2bf(v);
    v = acc[m][1][0]; if (RELU) v = fmaxf(v, 0.f); u1.x = f2bf(v);
    v = acc[m][1][1]; if (RELU) v = fmaxf(v, 0.f); u1.y = f2bf(v);
    v = acc[m][1][2]; if (RELU) v = fmaxf(v, 0.f); u1.z = f2bf(v);
    v = acc[m][1][3]; if (RELU) v = fmaxf(v, 0.f); u1.w = f2bf(v);
    *(ushort4*)o0 = u0;
    *(ushort4*)o1 = u1;
  }
}

// ======== dec_c3: LDS-free, short8 channel-octet loads (unchanged r7) ======
__global__ void __launch_bounds__(256) dec3_t(
    const unsigned short* __restrict__ p4, const float* __restrict__ w,
    const float* __restrict__ bias, float* __restrict__ out)
{
  int tid = threadIdx.x;
  int yr = tid >> 7, x = tid & 127;
  int y  = blockIdx.x * 2 + yr;
  int b  = blockIdx.z;

  const int kt[2][2] = {{1, 3}, {0, 2}};
  const int dt[2][2] = {{1, 0}, {2, 1}};

  const unsigned short* base[9];
  #pragma unroll
  for (int dy = 0; dy < 3; ++dy) {
    int iy = y + dy - 1;
    int py = iy & 1, u = iy >> 1;
    #pragma unroll
    for (int dx = 0; dx < 3; ++dx) {
      int ix = x + dx - 1;
      int px = ix & 1, v = ix >> 1;
      base[dy * 3 + dx] = p4 + ((size_t)(b * 4 + py * 2 + px) * 4356
                                + (size_t)(u + 1) * 66 + (v + 1)) * 64;
    }
  }

  float acc[4] = {0.f, 0.f, 0.f, 0.f};
  for (int oct = 0; oct < 8; ++oct) {
    ushort8 s[9];
    #pragma unroll
    for (int t = 0; t < 9; ++t)
      s[t] = *(const ushort8*)(base[t] + oct * 8);

    #pragma unroll
    for (int j = 0; j < 8; ++j) {
      const float* wp = w + (size_t)(oct * 8 + j) * 16;
      float v9[9];
      #pragma unroll
      for (int t = 0; t < 9; ++t) v9[t] = bf2f(s[t][j]);
      #pragma unroll
      for (int ry = 0; ry < 2; ++ry)
        #pragma unroll
        for (int rx = 0; rx < 2; ++rx)
          #pragma unroll
          for (int a = 0; a < 2; ++a)
            #pragma unroll
            for (int c2 = 0; c2 < 2; ++c2)
              acc[ry * 2 + rx] += v9[dt[ry][a] * 3 + dt[rx][c2]]
                                * wp[kt[ry][a] * 4 + kt[rx][c2]];
    }
  }

  float b0 = bias[0];
  float* ob = out + (size_t)b * 65536;
  #pragma unroll
  for (int ry = 0; ry < 2; ++ry)
    #pragma unroll
    for (int rx = 0; rx < 2; ++rx)
      ob[(2 * y + ry) * 256 + 2 * x + rx] = tanhf(acc[ry * 2 + rx] + b0);
}

// ======== aux: zero the pad ring of a padded-HWC bf16 buffer ===============
__global__ void ring2_k(unsigned short* __restrict__ buf, int icl, int H, int W)
{
  const int C = 1 << icl;
  unsigned short* p = buf + (size_t)blockIdx.x * H * W * C;
  int cells = 2 * W + 2 * (H - 2);
  int total = cells * C;
  for (int idx = threadIdx.x; idx < total; idx += 256) {
    int cell = idx >> icl;
    int e = idx & (C - 1);
    int row, col;
    if (cell < W)             { row = 0;     col = cell; }
    else if (cell < 2 * W)    { row = H - 1; col = cell - W; }
    else if (cell < 2 * W + (H - 2)) { row = cell - 2 * W + 1; col = 0; }
    else                      { row = cell - 2 * W - (H - 2) + 1; col = W - 1; }
    p[((size_t)row * W + col) * C + e] = 0;
  }
}

// ======== aux: repack decoder weights to bf16 [tap][oc][ic] (unchanged) ====
__global__ void repack_k(const float* __restrict__ c1w, const float* __restrict__ r1w,
                         const float* __restrict__ r2w, const float* __restrict__ c2w,
                         unsigned short* __restrict__ W)
{
  int idx = blockIdx.x * 256 + threadIdx.x;
  if (idx >= 286720) return;
  float val;
  if (idx < 73728) {
    int t = idx / 8192, rem = idx & 8191;
    int oc = rem >> 6, ic = rem & 63;
    int ky = t / 3, kx = t - ky * 3;
    val = c1w[((ic * 128 + oc) * 3 + (2 - ky)) * 3 + (2 - kx)];
  } else if (idx < 147456) {
    int j = idx - 73728;
    int t = j / 8192, rem = j & 8191;
    int oc = rem >> 7, ic = rem & 127;
    int ky = t / 3, kx = t - ky * 3;
    val = r1w[((oc * 128 + ic) * 3 + ky) * 3 + kx];
  } else if (idx < 155648) {
    int j = idx - 147456;
    int oc = j >> 6, ic = j & 63;
    val = r2w[oc * 64 + ic];
  } else {
    int j = idx - 155648;
    int p = j >> 15;
    int t2 = (j >> 13) & 3;
    int oc = (j >> 7) & 63;
    int ic = j & 127;
    int ry = p >> 1, rx = p & 1;
    int aY = t2 >> 1, aX = t2 & 1;
    int ky = aY ? (3 - ry) : (1 - ry);
    int kx = aX ? (3 - rx) : (1 - rx);
    val = c2w[((ic * 64 + oc) * 4 + ky) * 4 + kx];
  }
  W[idx] = f2bf(val);
}

// ======== aux: repack encoder weights to hi/lo [tap][oc][ic] ===============
// [0,131072) enc_c2 t16 oc128 ic64 | [131072,278528) enc_c3 t9 oc128 ic128 |
// [278528,352256) r1 t9 oc64 ic128 | [352256,360448) r2 oc128 ic64
__global__ void repack_enc_k(const float* __restrict__ c2w, const float* __restrict__ c3w,
                             const float* __restrict__ r1w, const float* __restrict__ r2w,
                             unsigned short* __restrict__ Wh, unsigned short* __restrict__ Wl)
{
  int idx = blockIdx.x * 256 + threadIdx.x;
  if (idx >= 360448) return;
  float val;
  if (idx < 131072) {
    int t = idx >> 13;
    int rem = idx & 8191;
    int oc = rem >> 6, ic = rem & 63;
    val = c2w[(((size_t)oc * 64 + ic) << 4) + t];
  } else if (idx < 278528) {
    int j = idx - 131072;
    int t = j / 16384;
    int rem = j & 16383;
    int oc = rem >> 7, ic = rem & 127;
    val = c3w[((size_t)oc * 128 + ic) * 9 + t];
  } else if (idx < 352256) {
    int j = idx - 278528;
    int t = j / 8192;
    int rem = j & 8191;
    int oc = rem >> 7, ic = rem & 127;
    val = r1w[((size_t)oc * 128 + ic) * 9 + t];
  } else {
    int j = idx - 352256;
    int oc = j >> 6, ic = j & 63;
    val = r2w[oc * 64 + ic];
  }
  unsigned short h = f2bf(val);
  Wh[idx] = h;
  Wl[idx] = f2bf(val - bf2f(h));
}

// ======== scratch init + scalar finalize ===================================
__global__ void init_k(float* sum_sq, int* hist)
{
  int t = threadIdx.x;
  if (t == 0) sum_sq[0] = 0.f;
  if (t < 64) hist[t] = 0;
}

__global__ void finalize_k(const float* __restrict__ sum_sq, const int* __restrict__ hist,
                           float* __restrict__ loss_out, float* __restrict__ perp_out)
{
  if (threadIdx.x == 0) {
    float mse = sum_sq[0] / (float)NELEM;
    loss_out[0] = 1.25f * mse;
    float ent = 0.f;
    for (int k = 0; k < 64; ++k) {
      float p = (float)hist[k] / (float)NPOS;
      ent += p * logf(p + 1e-10f);
    }
    perp_out[0] = expf(-ent);
  }
}

// ---------------------------------------------------------------------------
extern "C" void kernel_launch(void* const* d_in, const int* in_sizes, int n_in,
                              void* d_out, int out_size, void* d_ws, size_t ws_size,
                              hipStream_t stream)
{
  const float* x        = (const float*)d_in[0];
  const float* enc_c1_w = (const float*)d_in[1];
  const float* enc_c1_b = (const float*)d_in[2];
  const float* enc_c2_w = (const float*)d_in[3];
  const float* enc_c2_b = (const float*)d_in[4];
  const float* enc_c3_w = (const float*)d_in[5];
  const float* enc_c3_b = (const float*)d_in[6];
  const float* enc_r1_w = (const float*)d_in[7];
  const float* enc_r2_w = (const float*)d_in[8];
  const float* vqc_w    = (const float*)d_in[9];
  const float* vqc_b    = (const float*)d_in[10];
  const float* emb      = (const float*)d_in[11];
  const float* dec_c1_w = (const float*)d_in[12];
  const float* dec_c1_b = (const float*)d_in[13];
  const float* dec_r1_w = (const float*)d_in[14];
  const float* dec_r2_w = (const float*)d_in[15];
  const float* dec_c2_w = (const float*)d_in[16];
  const float* dec_c2_b = (const float*)d_in[17];
  const float* dec_c3_w = (const float*)d_in[18];
  const float* dec_c3_b = (const float*)d_in[19];

  float* out      = (float*)d_out;
  float* loss_out = out;
  float* xre_out  = out + 1;
  float* perp_out = out + 1 + 2097152;
  float* qn_out   = out + 2 + 2097152;

  float* sum_sq = (float*)d_ws;
  int*   hist   = (int*)d_ws + 1;
  char*  pool   = (char*)d_ws + 1024;

  // ---- pool layout (byte offsets; peak ~231 MB < proven 264 MB) ----
  unsigned short* Wd  = (unsigned short*)(pool + 0);           // 573,440 B
  unsigned short* Weh = (unsigned short*)(pool + 600000);      // 720,896 B
  unsigned short* Wel = (unsigned short*)(pool + 1400000);
  unsigned short* E1h = (unsigned short*)(pool + 2200000);     // 69.2 MB
  unsigned short* E1l = (unsigned short*)(pool + 71500000);
  unsigned short* B2h = (unsigned short*)(pool + 141000000);   // 35.7 MB
  unsigned short* B2l = (unsigned short*)(pool + 177000000);
  unsigned short* R0h = (unsigned short*)(pool + 2200000);     // over dead E1
  unsigned short* R0l = (unsigned short*)(pool + 38000000);
  unsigned short* Hh  = (unsigned short*)(pool + 74000000);    // 17.8 MB
  unsigned short* Hl  = (unsigned short*)(pool + 92000000);
  unsigned short* X1h = (unsigned short*)(pool + 141000000);   // over dead B2
  unsigned short* X1l = (unsigned short*)(pool + 177000000);
  unsigned short* X2h = (unsigned short*)(pool + 2200000);     // over dead R0
  unsigned short* X2l = (unsigned short*)(pool + 38000000);
  unsigned short* Dq  = (unsigned short*)(pool + 213000000);   // fresh, 17.8 MB
  unsigned short* Y1  = (unsigned short*)(pool + 141000000);   // over dead X1h
  unsigned short* S   = (unsigned short*)(pool + 110000000);   // fresh
  unsigned short* Y2  = (unsigned short*)(pool + 177000000);   // over dead X1l
  unsigned short* P4  = (unsigned short*)(pool + 2200000);     // over dead X2

  const int SS64  = 278784;
  const int SS128 = 557568;
  const int SSP4  = 1115136;

  hipLaunchKernelGGL(init_k, dim3(1), dim3(128), 0, stream, sum_sq, hist);
  hipLaunchKernelGGL(repack_k, dim3(1120), dim3(256), 0, stream,
                     dec_c1_w, dec_r1_w, dec_r2_w, dec_c2_w, Wd);
  hipLaunchKernelGGL(repack_enc_k, dim3(1408), dim3(256), 0, stream,
                     enc_c2_w, enc_c3_w, enc_r1_w, enc_r2_w, Weh, Wel);

  // rings for fresh regions (poisoned 0xAA each launch)
  hipLaunchKernelGGL(ring2_k, dim3(32), dim3(256), 0, stream, E1h, 6, 130, 130);
  hipLaunchKernelGGL(ring2_k, dim3(32), dim3(256), 0, stream, E1l, 6, 130, 130);
  hipLaunchKernelGGL(ring2_k, dim3(32), dim3(256), 0, stream, B2h, 7, 66, 66);
  hipLaunchKernelGGL(ring2_k, dim3(32), dim3(256), 0, stream, B2l, 7, 66, 66);
  hipLaunchKernelGGL(ring2_k, dim3(32), dim3(256), 0, stream, Dq, 6, 66, 66);

  // ---- encoder ----
  hipLaunchKernelGGL(enc1_t, dim3(64, 4, 32), dim3(256), 0, stream,
                     x, enc_c1_w, enc_c1_b, E1h, E1l);
  hipLaunchKernelGGL((mfma_enc<64, 128, 1, true, true>),
                     dim3(32, 1, 32), dim3(256), 0, stream,
                     E1h, E1l, Weh, Wel, enc_c2_b, nullptr, nullptr, B2h, B2l);

  // rings over regions freed by enc_c2 (E1 dead)
  hipLaunchKernelGGL(ring2_k, dim3(32), dim3(256), 0, stream, R0h, 7, 66, 66);
  hipLaunchKernelGGL(ring2_k, dim3(32), dim3(256), 0, stream, R0l, 7, 66, 66);
  hipLaunchKernelGGL(ring2_k, dim3(32), dim3(256), 0, stream, Hh, 6, 66, 66);
  hipLaunchKernelGGL(ring2_k, dim3(32), dim3(256), 0, stream, Hl, 6, 66, 66);
  hipLaunchKernelGGL(ring2_k, dim3(32), dim3(256), 0, stream, S, 6, 66, 66);

  hipLaunchKernelGGL((mfma_enc<128, 128, 0, true, true>),
                     dim3(32, 1, 32), dim3(256), 0, stream,
                     B2h, B2l, Weh + 131072, Wel + 131072, enc_c3_b,
                     nullptr, nullptr, R0h, R0l);

  hipLaunchKernelGGL(ring2_k, dim3(32), dim3(256), 0, stream, X1h, 7, 66, 66);
  hipLaunchKernelGGL(ring2_k, dim3(32), dim3(256), 0, stream, X1l, 7, 66, 66);

  hipLaunchKernelGGL((mfma_enc<128, 64, 0, false, true>),
                     dim3(32, 1, 32), dim3(256), 0, stream,
                     R0h, R0l, Weh + 278528, Wel + 278528, nullptr,
                     nullptr, nullptr, Hh, Hl);
  hipLaunchKernelGGL((mfma_enc<64, 128, 2, false, true>),
                     dim3(32, 1, 32), dim3(256), 0, stream,
                     Hh, Hl, Weh + 352256, Wel + 352256, nullptr,
                     R0h, R0l, X1h, X1l);

  hipLaunchKernelGGL(ring2_k, dim3(32), dim3(256), 0, stream, X2h, 7, 66, 66);
  hipLaunchKernelGGL(ring2_k, dim3(32), dim3(256), 0, stream, X2l, 7, 66, 66);

  hipLaunchKernelGGL((mfma_enc<128, 64, 0, false, true>),
                     dim3(32, 1, 32), dim3(256), 0, stream,
                     X1h, X1l, Weh + 278528, Wel + 278528, nullptr,
                     nullptr, nullptr, Hh, Hl);
  hipLaunchKernelGGL((mfma_enc<64, 128, 2, false, true>),
                     dim3(32, 1, 32), dim3(256), 0, stream,
                     Hh, Hl, Weh + 352256, Wel + 352256, nullptr,
                     X1h, X1l, X2h, X2l);

  // ---- VQ ----
  hipLaunchKernelGGL(vq_k, dim3(512), dim3(256), 0, stream,
                     X2h, X2l, vqc_w, vqc_b, emb, qn_out, Dq, sum_sq, hist);

  hipLaunchKernelGGL(ring2_k, dim3(32), dim3(256), 0, stream, Y1, 7, 66, 66);
  hipLaunchKernelGGL(ring2_k, dim3(32), dim3(256), 0, stream, Y2, 7, 66, 66);
  hipLaunchKernelGGL(ring2_k, dim3(128), dim3(256), 0, stream, P4, 6, 66, 66);

  // ---- decoder (bf16 MFMA, unchanged) ----
  hipLaunchKernelGGL((mfma_conv<64, 128, 0, true, false, true>),
                     dim3(32, 1, 32), dim3(256), 0, stream,
                     Dq, Wd, dec_c1_b, nullptr, Y1, 0, 0, SS64, SS128);
  hipLaunchKernelGGL((mfma_conv<128, 64, 0, false, false, true>),
                     dim3(32, 1, 32), dim3(256), 0, stream,
                     Y1, Wd + 73728, nullptr, nullptr, S, 0, 0, SS128, SS64);
  hipLaunchKernelGGL((mfma_conv<64, 128, 2, false, true, true>),
                     dim3(32, 1, 32), dim3(256), 0, stream,
                     S, Wd + 147456, nullptr, Y1, Y2, 0, 0, SS64, SS128);
  hipLaunchKernelGGL((mfma_conv<128, 64, 0, false, false, true>),
                     dim3(32, 1, 32), dim3(256), 0, stream,
                     Y2, Wd + 73728, nullptr, nullptr, S, 0, 0, SS128, SS64);
  hipLaunchKernelGGL((mfma_conv<64, 128, 2, false, true, true>),
                     dim3(32, 1, 32), dim3(256), 0, stream,
                     S, Wd + 147456, nullptr, Y2, Y1, 0, 0, SS64, SS128);

  for (int p = 0; p < 4; ++p) {
    hipLaunchKernelGGL((mfma_conv<128, 64, 1, true, false, true>),
                       dim3(32, 1, 32), dim3(256), 0, stream,
                       Y1, Wd + 155648 + p * 32768, dec_c2_b, nullptr,
                       P4 + (size_t)p * 4356 * 64, p >> 1, p & 1, SS128, SSP4);
  }

  hipLaunchKernelGGL(dec3_t, dim3(64, 1, 32), dim3(256), 0, stream,
                     P4, dec_c3_w, dec_c3_b, xre_out);

  hipLaunchKernelGGL(finalize_k, dim3(1), dim3(64), 0, stream,
                     sum_sq, hist, loss_out, perp_out);
}

// Round 9
// 1991.488 us; speedup vs baseline: 5.4049x; 1.2616x over previous
//
#include <hip/hip_runtime.h>
#include <cmath>

// ---------------------------------------------------------------------------
// VQ-VAE forward, round 9.
// Round-8: mfma_enc latency-bound (MfmaUtil 13%, VALUBusy 7%, occ 23%):
// 2 tiles/wave + 20 loads per 48 MFMAs and ~2 waves/SIMD can't cover L2
// latency. Fix: 4 tiles/wave (wave = one output row; block = 4 rows;
// grid.x 32->16) => 24 loads per 96 MFMAs, weights amortized 2x. Same for
// decoder mfma_conv. 17 ring-zero launches -> 5 multi-buffer launches.
// Encoder bf16x3 numerics and pool layout unchanged (validated r8).
// ---------------------------------------------------------------------------

static constexpr int NPOS  = 131072;
static constexpr long long NELEM = 8388608;

typedef __attribute__((ext_vector_type(8))) short short8;
typedef __attribute__((ext_vector_type(8))) unsigned short ushort8;
typedef __attribute__((ext_vector_type(4))) float f32x4;

__device__ __forceinline__ unsigned short f2bf(float f) {
  unsigned int x = __float_as_uint(f);
  unsigned int r = (x + 0x7fffu + ((x >> 16) & 1u)) >> 16;
  return (unsigned short)r;
}
__device__ __forceinline__ float bf2f(unsigned short u) {
  return __uint_as_float(((unsigned int)u) << 16);
}
__device__ __forceinline__ void split2(float v, unsigned short& h, unsigned short& l) {
  unsigned short hh = f2bf(v);
  h = hh;
  l = f2bf(v - bf2f(hh));
}

// ======== enc_c1: 4x4 s2 p1, (b,1,256,256) -> hi/lo HWC (130x130x64) =======
__global__ void __launch_bounds__(256) enc1_t(
    const float* __restrict__ in, const float* __restrict__ w,
    const float* __restrict__ bias,
    unsigned short* __restrict__ outh, unsigned short* __restrict__ outl)
{
  int tid = threadIdx.x;
  int rr = tid >> 7, ox = tid & 127;
  int oy  = blockIdx.x * 2 + rr;
  int oc0 = blockIdx.y * 16;
  int b   = blockIdx.z;

  const float* pl = in + (size_t)b * 65536;
  float v[16];
  #pragma unroll
  for (int ky = 0; ky < 4; ++ky) {
    int iy = 2 * oy - 1 + ky;
    #pragma unroll
    for (int kx = 0; kx < 4; ++kx) {
      int ix = 2 * ox - 1 + kx;
      v[ky * 4 + kx] = (iy >= 0 && iy < 256 && ix >= 0 && ix < 256)
                       ? pl[iy * 256 + ix] : 0.f;
    }
  }
  float acc[16];
  #pragma unroll
  for (int o = 0; o < 16; ++o) acc[o] = bias[oc0 + o];
  #pragma unroll
  for (int t = 0; t < 16; ++t)
    #pragma unroll
    for (int o = 0; o < 16; ++o)
      acc[o] += v[t] * w[(size_t)(oc0 + o) * 16 + t];

  size_t o = ((size_t)b * 16900 + (size_t)(oy + 1) * 130 + (ox + 1)) * 64 + oc0;
  ushort8 h0, h1, l0, l1;
  #pragma unroll
  for (int k = 0; k < 8; ++k) {
    unsigned short hh, ll;
    split2(fmaxf(acc[k], 0.f), hh, ll);      h0[k] = hh; l0[k] = ll;
    split2(fmaxf(acc[k + 8], 0.f), hh, ll);  h1[k] = hh; l1[k] = ll;
  }
  *(ushort8*)(outh + o)     = h0;
  *(ushort8*)(outh + o + 8) = h1;
  *(ushort8*)(outl + o)     = l0;
  *(ushort8*)(outl + o + 8) = l1;
}

// ======== bf16x3 MFMA tap-GEMM (encoder), 4 tiles/wave =====================
// MODE 0: 3x3 s1 (66-pad in). MODE 1: 4x4 s2 (130-pad in). MODE 2: 1x1+skip.
// grid (16,1,32); block 256 = 4 waves; wave = output row blockIdx.x*4+wv,
// tiles x = j*16 + l15, j=0..3.
template<int IC, int OC, int MODE, bool BIAS, bool RELU>
__global__ void __launch_bounds__(256) mfma_enc(
    const unsigned short* __restrict__ inh, const unsigned short* __restrict__ inl,
    const unsigned short* __restrict__ wh, const unsigned short* __restrict__ wl,
    const float* __restrict__ bias,
    const unsigned short* __restrict__ skh, const unsigned short* __restrict__ skl,
    unsigned short* __restrict__ outh, unsigned short* __restrict__ outl)
{
  constexpr int OM = OC / 16;
  constexpr int NT = (MODE == 0) ? 9 : ((MODE == 1) ? 16 : 1);
  constexpr int IW = (MODE == 1) ? 130 : 66;
  const int in_ss  = IW * IW * IC;
  const int out_ss = 4356 * OC;
  const int tid = threadIdx.x;
  const int wv = tid >> 6, lane = tid & 63;
  const int quad = lane >> 4, l15 = lane & 15;
  const int b = blockIdx.z;
  const int y = blockIdx.x * 4 + wv;
  int xs[4];
  #pragma unroll
  for (int j = 0; j < 4; ++j) xs[j] = j * 16 + l15;
  const unsigned short* ibh = inh + (size_t)b * in_ss;
  const unsigned short* ibl = inl + (size_t)b * in_ss;

  f32x4 acc[OM][4];
  #pragma unroll
  for (int m = 0; m < OM; ++m) {
    const int oc0 = m * 16 + quad * 4;
    f32x4 ini = {0.f, 0.f, 0.f, 0.f};
    if (BIAS) {
      float4 bs = *(const float4*)(bias + oc0);
      ini[0] = bs.x; ini[1] = bs.y; ini[2] = bs.z; ini[3] = bs.w;
    }
    #pragma unroll
    for (int j = 0; j < 4; ++j) {
      f32x4 a = ini;
      if (MODE == 2) {
        size_t s = (size_t)b * out_ss + ((size_t)(y + 1) * 66 + (xs[j] + 1)) * OC + oc0;
        ushort4 sh = *(const ushort4*)(skh + s);
        ushort4 sl = *(const ushort4*)(skl + s);
        a[0] += bf2f(sh.x) + bf2f(sl.x);
        a[1] += bf2f(sh.y) + bf2f(sl.y);
        a[2] += bf2f(sh.z) + bf2f(sl.z);
        a[3] += bf2f(sh.w) + bf2f(sl.w);
      }
      acc[m][j] = a;
    }
  }

  for (int t = 0; t < NT; ++t) {
    int off[4];
    #pragma unroll
    for (int j = 0; j < 4; ++j) {
      if (MODE == 1)
        off[j] = ((2 * y + (t >> 2)) * 130 + (2 * xs[j] + (t & 3))) * IC;
      else if (MODE == 0) {
        int dy = t / 3 - 1, dx = t % 3 - 1;
        off[j] = ((y + dy + 1) * 66 + (xs[j] + dx + 1)) * IC;
      } else
        off[j] = ((y + 1) * 66 + (xs[j] + 1)) * IC;
    }
    const unsigned short* wrh = wh + (size_t)t * OC * IC + l15 * IC + quad * 8;
    const unsigned short* wrl = wl + (size_t)t * OC * IC + l15 * IC + quad * 8;
    #pragma unroll
    for (int k0 = 0; k0 < IC; k0 += 32) {
      short8 bh[4], bl[4];
      #pragma unroll
      for (int j = 0; j < 4; ++j) {
        bh[j] = *(const short8*)(ibh + off[j] + quad * 8 + k0);
        bl[j] = *(const short8*)(ibl + off[j] + quad * 8 + k0);
      }
      #pragma unroll
      for (int m = 0; m < OM; ++m) {
        short8 ah = *(const short8*)(wrh + (size_t)m * 16 * IC + k0);
        short8 al = *(const short8*)(wrl + (size_t)m * 16 * IC + k0);
        #pragma unroll
        for (int j = 0; j < 4; ++j) {
          acc[m][j] = __builtin_amdgcn_mfma_f32_16x16x32_bf16(ah, bh[j], acc[m][j], 0, 0, 0);
          acc[m][j] = __builtin_amdgcn_mfma_f32_16x16x32_bf16(ah, bl[j], acc[m][j], 0, 0, 0);
          acc[m][j] = __builtin_amdgcn_mfma_f32_16x16x32_bf16(al, bh[j], acc[m][j], 0, 0, 0);
        }
      }
    }
  }

  #pragma unroll
  for (int m = 0; m < OM; ++m) {
    const int oc0 = m * 16 + quad * 4;
    #pragma unroll
    for (int j = 0; j < 4; ++j) {
      size_t o = (size_t)b * out_ss + ((size_t)(y + 1) * 66 + (xs[j] + 1)) * OC + oc0;
      ushort4 h4, l4;
      unsigned short hh, ll;
      float v;
      v = acc[m][j][0]; if (RELU) v = fmaxf(v, 0.f); split2(v, hh, ll); h4.x = hh; l4.x = ll;
      v = acc[m][j][1]; if (RELU) v = fmaxf(v, 0.f); split2(v, hh, ll); h4.y = hh; l4.y = ll;
      v = acc[m][j][2]; if (RELU) v = fmaxf(v, 0.f); split2(v, hh, ll); h4.z = hh; l4.z = ll;
      v = acc[m][j][3]; if (RELU) v = fmaxf(v, 0.f); split2(v, hh, ll); h4.w = hh; l4.w = ll;
      *(ushort4*)(outh + o) = h4;
      *(ushort4*)(outl + o) = l4;
    }
  }
}

// ======== fused pre-VQ 1x1 conv + VQ: hi/lo HWC in; qn fp32 + Dq bf16 ======
__global__ void __launch_bounds__(256, 2) vq_k(
    const unsigned short* __restrict__ xh, const unsigned short* __restrict__ xl,
    const float* __restrict__ vw, const float* __restrict__ vb,
    const float* __restrict__ emb,
    float* __restrict__ qn, unsigned short* __restrict__ dqb,
    float* __restrict__ sum_sq, int* __restrict__ hist)
{
  int tid = threadIdx.x;
  int n = blockIdx.x * 256 + tid;
  int b = n >> 12;
  int pos = n & 4095;
  int u = pos >> 6, v2 = pos & 63;

  float z[64];
  #pragma unroll
  for (int k = 0; k < 64; ++k) z[k] = vb[k];

  size_t ibase = ((size_t)b * 4356 + (size_t)(u + 1) * 66 + (v2 + 1)) * 128;
  for (int c0 = 0; c0 < 128; c0 += 8) {
    ushort8 hh = *(const ushort8*)(xh + ibase + c0);
    ushort8 ll = *(const ushort8*)(xl + ibase + c0);
    #pragma unroll
    for (int j = 0; j < 8; ++j) {
      float v = bf2f(hh[j]) + bf2f(ll[j]);
      #pragma unroll
      for (int k = 0; k < 64; ++k) z[k] += v * vw[k * 128 + c0 + j];
    }
  }

  float z2 = 0.f;
  #pragma unroll
  for (int d = 0; d < 64; ++d) z2 += z[d] * z[d];

  float best = INFINITY;
  int bidx = 0;
  for (int k = 0; k < 64; ++k) {
    float dot = 0.f, e2 = 0.f;
    #pragma unroll
    for (int d = 0; d < 64; ++d) {
      float e = emb[k * 64 + d];
      dot += z[d] * e;
      e2  += e * e;
    }
    float dist = z2 + e2 - 2.f * dot;
    if (dist < best) { best = dist; bidx = k; }
  }

  float sq = 0.f;
  const float* eb = emb + bidx * 64;
  float* qb = qn + (size_t)b * 262144 + pos;
  unsigned short* dq = dqb + (size_t)b * 278784 + ((size_t)(u + 1) * 66 + (v2 + 1)) * 64;
  #pragma unroll
  for (int d = 0; d < 64; ++d) {
    float e = eb[d];
    float df = e - z[d];
    sq += df * df;
    qb[(size_t)d * 4096] = e;
    dq[d] = f2bf(e);
  }

  __shared__ float red[256];
  __shared__ int lh[64];
  red[tid] = sq;
  if (tid < 64) lh[tid] = 0;
  __syncthreads();
  atomicAdd(&lh[bidx], 1);
  for (int s = 128; s > 0; s >>= 1) {
    if (tid < s) red[tid] += red[tid + s];
    __syncthreads();
  }
  if (tid == 0) atomicAdd(sum_sq, red[0]);
  if (tid < 64) atomicAdd(&hist[tid], lh[tid]);
}

// ======== bf16 MFMA tap-GEMM (decoder), 4 tiles/wave =======================
template<int IC, int OC, int MODE, bool HAS_BIAS, bool HAS_SKIP, bool RELU>
__global__ void __launch_bounds__(256) mfma_conv(
    const unsigned short* __restrict__ in, const unsigned short* __restrict__ wt,
    const float* __restrict__ bias, const unsigned short* __restrict__ skip,
    unsigned short* __restrict__ out, int ry, int rx, int in_ss, int out_ss)
{
  constexpr int OM = OC / 16;
  constexpr int NT = (MODE == 0) ? 9 : ((MODE == 1) ? 4 : 1);
  const int tid = threadIdx.x;
  const int wv = tid >> 6, lane = tid & 63;
  const int quad = lane >> 4, l15 = lane & 15;
  const int b = blockIdx.z;
  const int y = blockIdx.x * 4 + wv;
  int xs[4];
  #pragma unroll
  for (int j = 0; j < 4; ++j) xs[j] = j * 16 + l15;
  const unsigned short* inb = in + (size_t)b * (size_t)in_ss;

  f32x4 acc[OM][4];
  #pragma unroll
  for (int m = 0; m < OM; ++m) {
    const int oc0 = m * 16 + quad * 4;
    f32x4 ini = {0.f, 0.f, 0.f, 0.f};
    if (HAS_BIAS) {
      float4 bs = *(const float4*)(bias + oc0);
      ini[0] = bs.x; ini[1] = bs.y; ini[2] = bs.z; ini[3] = bs.w;
    }
    #pragma unroll
    for (int j = 0; j < 4; ++j) {
      f32x4 a = ini;
      if (HAS_SKIP) {
        size_t s = (size_t)b * (size_t)out_ss + ((size_t)(y + 1) * 66 + (xs[j] + 1)) * OC + oc0;
        ushort4 sv = *(const ushort4*)(skip + s);
        a[0] += bf2f(sv.x); a[1] += bf2f(sv.y); a[2] += bf2f(sv.z); a[3] += bf2f(sv.w);
      }
      acc[m][j] = a;
    }
  }

  #pragma unroll
  for (int t = 0; t < NT; ++t) {
    const int dy = (MODE == 0) ? (t / 3 - 1) : ((MODE == 1) ? (ry - (t >> 1)) : 0);
    const int dx = (MODE == 0) ? (t % 3 - 1) : ((MODE == 1) ? (rx - (t & 1)) : 0);
    const unsigned short* wr = wt + (size_t)t * OC * IC + (size_t)l15 * IC + quad * 8;
    #pragma unroll
    for (int k0 = 0; k0 < IC; k0 += 32) {
      short8 fb[4];
      #pragma unroll
      for (int j = 0; j < 4; ++j)
        fb[j] = *(const short8*)(inb + ((size_t)(y + dy + 1) * 66 + (xs[j] + dx + 1)) * IC + quad * 8 + k0);
      #pragma unroll
      for (int m = 0; m < OM; ++m) {
        short8 fa = *(const short8*)(wr + (size_t)m * 16 * IC + k0);
        #pragma unroll
        for (int j = 0; j < 4; ++j)
          acc[m][j] = __builtin_amdgcn_mfma_f32_16x16x32_bf16(fa, fb[j], acc[m][j], 0, 0, 0);
      }
    }
  }

  #pragma unroll
  for (int m = 0; m < OM; ++m) {
    const int oc0 = m * 16 + quad * 4;
    #pragma unroll
    for (int j = 0; j < 4; ++j) {
      unsigned short* o = out + (size_t)b * (size_t)out_ss
                        + ((size_t)(y + 1) * 66 + (xs[j] + 1)) * OC + oc0;
      ushort4 u4;
      float v;
      v = acc[m][j][0]; if (RELU) v = fmaxf(v, 0.f); u4.x = f2bf(v);
      v = acc[m][j][1]; if (RELU) v = fmaxf(v, 0.f); u4.y = f2bf(v);
      v = acc[m][j][2]; if (RELU) v = fmaxf(v, 0.f); u4.z = f2bf(v);
      v = acc[m][j][3]; if (RELU) v = fmaxf(v, 0.f); u4.w = f2bf(v);
      *(ushort4*)o = u4;
    }
  }
}

// ======== dec_c3: LDS-free, short8 channel-octet loads (unchanged r7/r8) ===
__global__ void __launch_bounds__(256) dec3_t(
    const unsigned short* __restrict__ p4, const float* __restrict__ w,
    const float* __restrict__ bias, float* __restrict__ out)
{
  int tid = threadIdx.x;
  int yr = tid >> 7, x = tid & 127;
  int y  = blockIdx.x * 2 + yr;
  int b  = blockIdx.z;

  const int kt[2][2] = {{1, 3}, {0, 2}};
  const int dt[2][2] = {{1, 0}, {2, 1}};

  const unsigned short* base[9];
  #pragma unroll
  for (int dy = 0; dy < 3; ++dy) {
    int iy = y + dy - 1;
    int py = iy & 1, u = iy >> 1;
    #pragma unroll
    for (int dx = 0; dx < 3; ++dx) {
      int ix = x + dx - 1;
      int px = ix & 1, v = ix >> 1;
      base[dy * 3 + dx] = p4 + ((size_t)(b * 4 + py * 2 + px) * 4356
                                + (size_t)(u + 1) * 66 + (v + 1)) * 64;
    }
  }

  float acc[4] = {0.f, 0.f, 0.f, 0.f};
  for (int oct = 0; oct < 8; ++oct) {
    ushort8 s[9];
    #pragma unroll
    for (int t = 0; t < 9; ++t)
      s[t] = *(const ushort8*)(base[t] + oct * 8);

    #pragma unroll
    for (int j = 0; j < 8; ++j) {
      const float* wp = w + (size_t)(oct * 8 + j) * 16;
      float v9[9];
      #pragma unroll
      for (int t = 0; t < 9; ++t) v9[t] = bf2f(s[t][j]);
      #pragma unroll
      for (int ry = 0; ry < 2; ++ry)
        #pragma unroll
        for (int rx = 0; rx < 2; ++rx)
          #pragma unroll
          for (int a = 0; a < 2; ++a)
            #pragma unroll
            for (int c2 = 0; c2 < 2; ++c2)
              acc[ry * 2 + rx] += v9[dt[ry][a] * 3 + dt[rx][c2]]
                                * wp[kt[ry][a] * 4 + kt[rx][c2]];
    }
  }

  float b0 = bias[0];
  float* ob = out + (size_t)b * 65536;
  #pragma unroll
  for (int ry = 0; ry < 2; ++ry)
    #pragma unroll
    for (int rx = 0; rx < 2; ++rx)
      ob[(2 * y + ry) * 256 + 2 * x + rx] = tanhf(acc[ry * 2 + rx] + b0);
}

// ======== aux: multi-buffer pad-ring zero ==================================
struct RingArgs {
  unsigned short* p[5];
  int icl[5];
  int H[5];
  int planes[5];
};
__global__ void rings_k(RingArgs a)
{
  int bi = blockIdx.y;
  if ((int)blockIdx.x >= a.planes[bi]) return;
  int H = a.H[bi];
  int icl = a.icl[bi];
  int C = 1 << icl;
  unsigned short* pl = a.p[bi] + (size_t)blockIdx.x * H * H * C;
  int cells = 4 * H - 4;
  int total = cells * C;
  for (int idx = threadIdx.x; idx < total; idx += 256) {
    int cell = idx >> icl;
    int e = idx & (C - 1);
    int row, col;
    if (cell < H)             { row = 0;     col = cell; }
    else if (cell < 2 * H)    { row = H - 1; col = cell - H; }
    else if (cell < 2 * H + (H - 2)) { row = cell - 2 * H + 1; col = 0; }
    else                      { row = cell - 2 * H - (H - 2) + 1; col = H - 1; }
    pl[((size_t)row * H + col) * C + e] = 0;
  }
}

// ======== aux: repack decoder weights to bf16 [tap][oc][ic] (unchanged) ====
__global__ void repack_k(const float* __restrict__ c1w, const float* __restrict__ r1w,
                         const float* __restrict__ r2w, const float* __restrict__ c2w,
                         unsigned short* __restrict__ W)
{
  int idx = blockIdx.x * 256 + threadIdx.x;
  if (idx >= 286720) return;
  float val;
  if (idx < 73728) {
    int t = idx / 8192, rem = idx & 8191;
    int oc = rem >> 6, ic = rem & 63;
    int ky = t / 3, kx = t - ky * 3;
    val = c1w[((ic * 128 + oc) * 3 + (2 - ky)) * 3 + (2 - kx)];
  } else if (idx < 147456) {
    int j = idx - 73728;
    int t = j / 8192, rem = j & 8191;
    int oc = rem >> 7, ic = rem & 127;
    int ky = t / 3, kx = t - ky * 3;
    val = r1w[((oc * 128 + ic) * 3 + ky) * 3 + kx];
  } else if (idx < 155648) {
    int j = idx - 147456;
    int oc = j >> 6, ic = j & 63;
    val = r2w[oc * 64 + ic];
  } else {
    int j = idx - 155648;
    int p = j >> 15;
    int t2 = (j >> 13) & 3;
    int oc = (j >> 7) & 63;
    int ic = j & 127;
    int ry = p >> 1, rx = p & 1;
    int aY = t2 >> 1, aX = t2 & 1;
    int ky = aY ? (3 - ry) : (1 - ry);
    int kx = aX ? (3 - rx) : (1 - rx);
    val = c2w[((ic * 64 + oc) * 4 + ky) * 4 + kx];
  }
  W[idx] = f2bf(val);
}

// ======== aux: repack encoder weights to hi/lo [tap][oc][ic] (unchanged) ===
__global__ void repack_enc_k(const float* __restrict__ c2w, const float* __restrict__ c3w,
                             const float* __restrict__ r1w, const float* __restrict__ r2w,
                             unsigned short* __restrict__ Wh, unsigned short* __restrict__ Wl)
{
  int idx = blockIdx.x * 256 + threadIdx.x;
  if (idx >= 360448) return;
  float val;
  if (idx < 131072) {
    int t = idx >> 13;
    int rem = idx & 8191;
    int oc = rem >> 6, ic = rem & 63;
    val = c2w[(((size_t)oc * 64 + ic) << 4) + t];
  } else if (idx < 278528) {
    int j = idx - 131072;
    int t = j / 16384;
    int rem = j & 16383;
    int oc = rem >> 7, ic = rem & 127;
    val = c3w[((size_t)oc * 128 + ic) * 9 + t];
  } else if (idx < 352256) {
    int j = idx - 278528;
    int t = j / 8192;
    int rem = j & 8191;
    int oc = rem >> 7, ic = rem & 127;
    val = r1w[((size_t)oc * 128 + ic) * 9 + t];
  } else {
    int j = idx - 352256;
    int oc = j >> 6, ic = j & 63;
    val = r2w[oc * 64 + ic];
  }
  unsigned short h = f2bf(val);
  Wh[idx] = h;
  Wl[idx] = f2bf(val - bf2f(h));
}

// ======== scratch init + scalar finalize ===================================
__global__ void init_k(float* sum_sq, int* hist)
{
  int t = threadIdx.x;
  if (t == 0) sum_sq[0] = 0.f;
  if (t < 64) hist[t] = 0;
}

__global__ void finalize_k(const float* __restrict__ sum_sq, const int* __restrict__ hist,
                           float* __restrict__ loss_out, float* __restrict__ perp_out)
{
  if (threadIdx.x == 0) {
    float mse = sum_sq[0] / (float)NELEM;
    loss_out[0] = 1.25f * mse;
    float ent = 0.f;
    for (int k = 0; k < 64; ++k) {
      float p = (float)hist[k] / (float)NPOS;
      ent += p * logf(p + 1e-10f);
    }
    perp_out[0] = expf(-ent);
  }
}

// ---------------------------------------------------------------------------
extern "C" void kernel_launch(void* const* d_in, const int* in_sizes, int n_in,
                              void* d_out, int out_size, void* d_ws, size_t ws_size,
                              hipStream_t stream)
{
  const float* x        = (const float*)d_in[0];
  const float* enc_c1_w = (const float*)d_in[1];
  const float* enc_c1_b = (const float*)d_in[2];
  const float* enc_c2_w = (const float*)d_in[3];
  const float* enc_c2_b = (const float*)d_in[4];
  const float* enc_c3_w = (const float*)d_in[5];
  const float* enc_c3_b = (const float*)d_in[6];
  const float* enc_r1_w = (const float*)d_in[7];
  const float* enc_r2_w = (const float*)d_in[8];
  const float* vqc_w    = (const float*)d_in[9];
  const float* vqc_b    = (const float*)d_in[10];
  const float* emb      = (const float*)d_in[11];
  const float* dec_c1_w = (const float*)d_in[12];
  const float* dec_c1_b = (const float*)d_in[13];
  const float* dec_r1_w = (const float*)d_in[14];
  const float* dec_r2_w = (const float*)d_in[15];
  const float* dec_c2_w = (const float*)d_in[16];
  const float* dec_c2_b = (const float*)d_in[17];
  const float* dec_c3_w = (const float*)d_in[18];
  const float* dec_c3_b = (const float*)d_in[19];

  float* out      = (float*)d_out;
  float* loss_out = out;
  float* xre_out  = out + 1;
  float* perp_out = out + 1 + 2097152;
  float* qn_out   = out + 2 + 2097152;

  float* sum_sq = (float*)d_ws;
  int*   hist   = (int*)d_ws + 1;
  char*  pool   = (char*)d_ws + 1024;

  unsigned short* Wd  = (unsigned short*)(pool + 0);
  unsigned short* Weh = (unsigned short*)(pool + 600000);
  unsigned short* Wel = (unsigned short*)(pool + 1400000);
  unsigned short* E1h = (unsigned short*)(pool + 2200000);
  unsigned short* E1l = (unsigned short*)(pool + 71500000);
  unsigned short* B2h = (unsigned short*)(pool + 141000000);
  unsigned short* B2l = (unsigned short*)(pool + 177000000);
  unsigned short* R0h = (unsigned short*)(pool + 2200000);
  unsigned short* R0l = (unsigned short*)(pool + 38000000);
  unsigned short* Hh  = (unsigned short*)(pool + 74000000);
  unsigned short* Hl  = (unsigned short*)(pool + 92000000);
  unsigned short* X1h = (unsigned short*)(pool + 141000000);
  unsigned short* X1l = (unsigned short*)(pool + 177000000);
  unsigned short* X2h = (unsigned short*)(pool + 2200000);
  unsigned short* X2l = (unsigned short*)(pool + 38000000);
  unsigned short* Dq  = (unsigned short*)(pool + 213000000);
  unsigned short* Y1  = (unsigned short*)(pool + 141000000);
  unsigned short* S   = (unsigned short*)(pool + 110000000);
  unsigned short* Y2  = (unsigned short*)(pool + 177000000);
  unsigned short* P4  = (unsigned short*)(pool + 2200000);

  const int SS64  = 278784;
  const int SS128 = 557568;
  const int SSP4  = 1115136;

  hipLaunchKernelGGL(init_k, dim3(1), dim3(128), 0, stream, sum_sq, hist);
  hipLaunchKernelGGL(repack_k, dim3(1120), dim3(256), 0, stream,
                     dec_c1_w, dec_r1_w, dec_r2_w, dec_c2_w, Wd);
  hipLaunchKernelGGL(repack_enc_k, dim3(1408), dim3(256), 0, stream,
                     enc_c2_w, enc_c3_w, enc_r1_w, enc_r2_w, Weh, Wel);

  // rings group 1: fresh regions
  {
    RingArgs a;
    a.p[0] = E1h; a.icl[0] = 6; a.H[0] = 130; a.planes[0] = 32;
    a.p[1] = E1l; a.icl[1] = 6; a.H[1] = 130; a.planes[1] = 32;
    a.p[2] = B2h; a.icl[2] = 7; a.H[2] = 66;  a.planes[2] = 32;
    a.p[3] = B2l; a.icl[3] = 7; a.H[3] = 66;  a.planes[3] = 32;
    a.p[4] = Dq;  a.icl[4] = 6; a.H[4] = 66;  a.planes[4] = 32;
    hipLaunchKernelGGL(rings_k, dim3(32, 5), dim3(256), 0, stream, a);
  }

  // ---- encoder ----
  hipLaunchKernelGGL(enc1_t, dim3(64, 4, 32), dim3(256), 0, stream,
                     x, enc_c1_w, enc_c1_b, E1h, E1l);
  hipLaunchKernelGGL((mfma_enc<64, 128, 1, true, true>),
                     dim3(16, 1, 32), dim3(256), 0, stream,
                     E1h, E1l, Weh, Wel, enc_c2_b, nullptr, nullptr, B2h, B2l);

  // rings group 2: regions freed by enc_c2 (E1 dead)
  {
    RingArgs a;
    a.p[0] = R0h; a.icl[0] = 7; a.H[0] = 66; a.planes[0] = 32;
    a.p[1] = R0l; a.icl[1] = 7; a.H[1] = 66; a.planes[1] = 32;
    a.p[2] = Hh;  a.icl[2] = 6; a.H[2] = 66; a.planes[2] = 32;
    a.p[3] = Hl;  a.icl[3] = 6; a.H[3] = 66; a.planes[3] = 32;
    a.p[4] = S;   a.icl[4] = 6; a.H[4] = 66; a.planes[4] = 32;
    hipLaunchKernelGGL(rings_k, dim3(32, 5), dim3(256), 0, stream, a);
  }

  hipLaunchKernelGGL((mfma_enc<128, 128, 0, true, true>),
                     dim3(16, 1, 32), dim3(256), 0, stream,
                     B2h, B2l, Weh + 131072, Wel + 131072, enc_c3_b,
                     nullptr, nullptr, R0h, R0l);

  // rings group 3: X1 over dead B2
  {
    RingArgs a;
    a.p[0] = X1h; a.icl[0] = 7; a.H[0] = 66; a.planes[0] = 32;
    a.p[1] = X1l; a.icl[1] = 7; a.H[1] = 66; a.planes[1] = 32;
    a.p[2] = nullptr; a.icl[2] = 0; a.H[2] = 2; a.planes[2] = 0;
    a.p[3] = nullptr; a.icl[3] = 0; a.H[3] = 2; a.planes[3] = 0;
    a.p[4] = nullptr; a.icl[4] = 0; a.H[4] = 2; a.planes[4] = 0;
    hipLaunchKernelGGL(rings_k, dim3(32, 2), dim3(256), 0, stream, a);
  }

  hipLaunchKernelGGL((mfma_enc<128, 64, 0, false, true>),
                     dim3(16, 1, 32), dim3(256), 0, stream,
                     R0h, R0l, Weh + 278528, Wel + 278528, nullptr,
                     nullptr, nullptr, Hh, Hl);
  hipLaunchKernelGGL((mfma_enc<64, 128, 2, false, true>),
                     dim3(16, 1, 32), dim3(256), 0, stream,
                     Hh, Hl, Weh + 352256, Wel + 352256, nullptr,
                     R0h, R0l, X1h, X1l);

  // rings group 4: X2 over dead R0
  {
    RingArgs a;
    a.p[0] = X2h; a.icl[0] = 7; a.H[0] = 66; a.planes[0] = 32;
    a.p[1] = X2l; a.icl[1] = 7; a.H[1] = 66; a.planes[1] = 32;
    a.p[2] = nullptr; a.icl[2] = 0; a.H[2] = 2; a.planes[2] = 0;
    a.p[3] = nullptr; a.icl[3] = 0; a.H[3] = 2; a.planes[3] = 0;
    a.p[4] = nullptr; a.icl[4] = 0; a.H[4] = 2; a.planes[4] = 0;
    hipLaunchKernelGGL(rings_k, dim3(32, 2), dim3(256), 0, stream, a);
  }

  hipLaunchKernelGGL((mfma_enc<128, 64, 0, false, true>),
                     dim3(16, 1, 32), dim3(256), 0, stream,
                     X1h, X1l, Weh + 278528, Wel + 278528, nullptr,
                     nullptr, nullptr, Hh, Hl);
  hipLaunchKernelGGL((mfma_enc<64, 128, 2, false, true>),
                     dim3(16, 1, 32), dim3(256), 0, stream,
                     Hh, Hl, Weh + 352256, Wel + 352256, nullptr,
                     X1h, X1l, X2h, X2l);

  // ---- VQ ----
  hipLaunchKernelGGL(vq_k, dim3(512), dim3(256), 0, stream,
                     X2h, X2l, vqc_w, vqc_b, emb, qn_out, Dq, sum_sq, hist);

  // rings group 5: decoder regions (X1, X2 dead)
  {
    RingArgs a;
    a.p[0] = Y1;  a.icl[0] = 7; a.H[0] = 66; a.planes[0] = 32;
    a.p[1] = Y2;  a.icl[1] = 7; a.H[1] = 66; a.planes[1] = 32;
    a.p[2] = P4;  a.icl[2] = 6; a.H[2] = 66; a.planes[2] = 128;
    a.p[3] = nullptr; a.icl[3] = 0; a.H[3] = 2; a.planes[3] = 0;
    a.p[4] = nullptr; a.icl[4] = 0; a.H[4] = 2; a.planes[4] = 0;
    hipLaunchKernelGGL(rings_k, dim3(128, 3), dim3(256), 0, stream, a);
  }

  // ---- decoder (bf16 MFMA, 4 tiles/wave) ----
  hipLaunchKernelGGL((mfma_conv<64, 128, 0, true, false, true>),
                     dim3(16, 1, 32), dim3(256), 0, stream,
                     Dq, Wd, dec_c1_b, nullptr, Y1, 0, 0, SS64, SS128);
  hipLaunchKernelGGL((mfma_conv<128, 64, 0, false, false, true>),
                     dim3(16, 1, 32), dim3(256), 0, stream,
                     Y1, Wd + 73728, nullptr, nullptr, S, 0, 0, SS128, SS64);
  hipLaunchKernelGGL((mfma_conv<64, 128, 2, false, true, true>),
                     dim3(16, 1, 32), dim3(256), 0, stream,
                     S, Wd + 147456, nullptr, Y1, Y2, 0, 0, SS64, SS128);
  hipLaunchKernelGGL((mfma_conv<128, 64, 0, false, false, true>),
                     dim3(16, 1, 32), dim3(256), 0, stream,
                     Y2, Wd + 73728, nullptr, nullptr, S, 0, 0, SS128, SS64);
  hipLaunchKernelGGL((mfma_conv<64, 128, 2, false, true, true>),
                     dim3(16, 1, 32), dim3(256), 0, stream,
                     S, Wd + 147456, nullptr, Y2, Y1, 0, 0, SS64, SS128);

  for (int p = 0; p < 4; ++p) {
    hipLaunchKernelGGL((mfma_conv<128, 64, 1, true, false, true>),
                       dim3(16, 1, 32), dim3(256), 0, stream,
                       Y1, Wd + 155648 + p * 32768, dec_c2_b, nullptr,
                       P4 + (size_t)p * 4356 * 64, p >> 1, p & 1, SS128, SSP4);
  }

  hipLaunchKernelGGL(dec3_t, dim3(64, 1, 32), dim3(256), 0, stream,
                     P4, dec_c3_w, dec_c3_b, xre_out);

  hipLaunchKernelGGL(finalize_k, dim3(1), dim3(64), 0, stream,
                     sum_sq, hist, loss_out, perp_out);
}

// Round 10
// 1870.697 us; speedup vs baseline: 5.7539x; 1.0646x over previous
//
#include <hip/hip_runtime.h>
#include <cmath>

// ---------------------------------------------------------------------------
// VQ-VAE forward, round 10.
// Round-9: vq_k top kernel (303us, VALUBusy 34%, VGPR 56 => z[64] spilled to
// scratch, FETCH 117MB vs 71MB real). Rewritten on MFMA: wave = 16 positions;
// GEMM1 z=X@W^T (bf16x3), LDS round-trip to B-layout, GEMM2 scores=z@emb^T
// (bf16x3), dist via |z|^2 butterfly + e2 table, argmin with first-index
// tie-break, fused epilogue (qn fp32, Dq bf16, sum_sq, hist).
// dec_c2 parity launches merged into one (grid.y=4). Rest unchanged (r9).
// ---------------------------------------------------------------------------

static constexpr int NPOS  = 131072;
static constexpr long long NELEM = 8388608;

typedef __attribute__((ext_vector_type(8))) short short8;
typedef __attribute__((ext_vector_type(8))) unsigned short ushort8;
typedef __attribute__((ext_vector_type(4))) float f32x4;

__device__ __forceinline__ unsigned short f2bf(float f) {
  unsigned int x = __float_as_uint(f);
  unsigned int r = (x + 0x7fffu + ((x >> 16) & 1u)) >> 16;
  return (unsigned short)r;
}
__device__ __forceinline__ float bf2f(unsigned short u) {
  return __uint_as_float(((unsigned int)u) << 16);
}
__device__ __forceinline__ void split2(float v, unsigned short& h, unsigned short& l) {
  unsigned short hh = f2bf(v);
  h = hh;
  l = f2bf(v - bf2f(hh));
}

// ======== enc_c1: 4x4 s2 p1, (b,1,256,256) -> hi/lo HWC (130x130x64) =======
__global__ void __launch_bounds__(256) enc1_t(
    const float* __restrict__ in, const float* __restrict__ w,
    const float* __restrict__ bias,
    unsigned short* __restrict__ outh, unsigned short* __restrict__ outl)
{
  int tid = threadIdx.x;
  int rr = tid >> 7, ox = tid & 127;
  int oy  = blockIdx.x * 2 + rr;
  int oc0 = blockIdx.y * 16;
  int b   = blockIdx.z;

  const float* pl = in + (size_t)b * 65536;
  float v[16];
  #pragma unroll
  for (int ky = 0; ky < 4; ++ky) {
    int iy = 2 * oy - 1 + ky;
    #pragma unroll
    for (int kx = 0; kx < 4; ++kx) {
      int ix = 2 * ox - 1 + kx;
      v[ky * 4 + kx] = (iy >= 0 && iy < 256 && ix >= 0 && ix < 256)
                       ? pl[iy * 256 + ix] : 0.f;
    }
  }
  float acc[16];
  #pragma unroll
  for (int o = 0; o < 16; ++o) acc[o] = bias[oc0 + o];
  #pragma unroll
  for (int t = 0; t < 16; ++t)
    #pragma unroll
    for (int o = 0; o < 16; ++o)
      acc[o] += v[t] * w[(size_t)(oc0 + o) * 16 + t];

  size_t o = ((size_t)b * 16900 + (size_t)(oy + 1) * 130 + (ox + 1)) * 64 + oc0;
  ushort8 h0, h1, l0, l1;
  #pragma unroll
  for (int k = 0; k < 8; ++k) {
    unsigned short hh, ll;
    split2(fmaxf(acc[k], 0.f), hh, ll);      h0[k] = hh; l0[k] = ll;
    split2(fmaxf(acc[k + 8], 0.f), hh, ll);  h1[k] = hh; l1[k] = ll;
  }
  *(ushort8*)(outh + o)     = h0;
  *(ushort8*)(outh + o + 8) = h1;
  *(ushort8*)(outl + o)     = l0;
  *(ushort8*)(outl + o + 8) = l1;
}

// ======== bf16x3 MFMA tap-GEMM (encoder), 4 tiles/wave (unchanged r9) ======
template<int IC, int OC, int MODE, bool BIAS, bool RELU>
__global__ void __launch_bounds__(256) mfma_enc(
    const unsigned short* __restrict__ inh, const unsigned short* __restrict__ inl,
    const unsigned short* __restrict__ wh, const unsigned short* __restrict__ wl,
    const float* __restrict__ bias,
    const unsigned short* __restrict__ skh, const unsigned short* __restrict__ skl,
    unsigned short* __restrict__ outh, unsigned short* __restrict__ outl)
{
  constexpr int OM = OC / 16;
  constexpr int NT = (MODE == 0) ? 9 : ((MODE == 1) ? 16 : 1);
  constexpr int IW = (MODE == 1) ? 130 : 66;
  const int in_ss  = IW * IW * IC;
  const int out_ss = 4356 * OC;
  const int tid = threadIdx.x;
  const int wv = tid >> 6, lane = tid & 63;
  const int quad = lane >> 4, l15 = lane & 15;
  const int b = blockIdx.z;
  const int y = blockIdx.x * 4 + wv;
  int xs[4];
  #pragma unroll
  for (int j = 0; j < 4; ++j) xs[j] = j * 16 + l15;
  const unsigned short* ibh = inh + (size_t)b * in_ss;
  const unsigned short* ibl = inl + (size_t)b * in_ss;

  f32x4 acc[OM][4];
  #pragma unroll
  for (int m = 0; m < OM; ++m) {
    const int oc0 = m * 16 + quad * 4;
    f32x4 ini = {0.f, 0.f, 0.f, 0.f};
    if (BIAS) {
      float4 bs = *(const float4*)(bias + oc0);
      ini[0] = bs.x; ini[1] = bs.y; ini[2] = bs.z; ini[3] = bs.w;
    }
    #pragma unroll
    for (int j = 0; j < 4; ++j) {
      f32x4 a = ini;
      if (MODE == 2) {
        size_t s = (size_t)b * out_ss + ((size_t)(y + 1) * 66 + (xs[j] + 1)) * OC + oc0;
        ushort4 sh = *(const ushort4*)(skh + s);
        ushort4 sl = *(const ushort4*)(skl + s);
        a[0] += bf2f(sh.x) + bf2f(sl.x);
        a[1] += bf2f(sh.y) + bf2f(sl.y);
        a[2] += bf2f(sh.z) + bf2f(sl.z);
        a[3] += bf2f(sh.w) + bf2f(sl.w);
      }
      acc[m][j] = a;
    }
  }

  for (int t = 0; t < NT; ++t) {
    int off[4];
    #pragma unroll
    for (int j = 0; j < 4; ++j) {
      if (MODE == 1)
        off[j] = ((2 * y + (t >> 2)) * 130 + (2 * xs[j] + (t & 3))) * IC;
      else if (MODE == 0) {
        int dy = t / 3 - 1, dx = t % 3 - 1;
        off[j] = ((y + dy + 1) * 66 + (xs[j] + dx + 1)) * IC;
      } else
        off[j] = ((y + 1) * 66 + (xs[j] + 1)) * IC;
    }
    const unsigned short* wrh = wh + (size_t)t * OC * IC + l15 * IC + quad * 8;
    const unsigned short* wrl = wl + (size_t)t * OC * IC + l15 * IC + quad * 8;
    #pragma unroll
    for (int k0 = 0; k0 < IC; k0 += 32) {
      short8 bh[4], bl[4];
      #pragma unroll
      for (int j = 0; j < 4; ++j) {
        bh[j] = *(const short8*)(ibh + off[j] + quad * 8 + k0);
        bl[j] = *(const short8*)(ibl + off[j] + quad * 8 + k0);
      }
      #pragma unroll
      for (int m = 0; m < OM; ++m) {
        short8 ah = *(const short8*)(wrh + (size_t)m * 16 * IC + k0);
        short8 al = *(const short8*)(wrl + (size_t)m * 16 * IC + k0);
        #pragma unroll
        for (int j = 0; j < 4; ++j) {
          acc[m][j] = __builtin_amdgcn_mfma_f32_16x16x32_bf16(ah, bh[j], acc[m][j], 0, 0, 0);
          acc[m][j] = __builtin_amdgcn_mfma_f32_16x16x32_bf16(ah, bl[j], acc[m][j], 0, 0, 0);
          acc[m][j] = __builtin_amdgcn_mfma_f32_16x16x32_bf16(al, bh[j], acc[m][j], 0, 0, 0);
        }
      }
    }
  }

  #pragma unroll
  for (int m = 0; m < OM; ++m) {
    const int oc0 = m * 16 + quad * 4;
    #pragma unroll
    for (int j = 0; j < 4; ++j) {
      size_t o = (size_t)b * out_ss + ((size_t)(y + 1) * 66 + (xs[j] + 1)) * OC + oc0;
      ushort4 h4, l4;
      unsigned short hh, ll;
      float v;
      v = acc[m][j][0]; if (RELU) v = fmaxf(v, 0.f); split2(v, hh, ll); h4.x = hh; l4.x = ll;
      v = acc[m][j][1]; if (RELU) v = fmaxf(v, 0.f); split2(v, hh, ll); h4.y = hh; l4.y = ll;
      v = acc[m][j][2]; if (RELU) v = fmaxf(v, 0.f); split2(v, hh, ll); h4.z = hh; l4.z = ll;
      v = acc[m][j][3]; if (RELU) v = fmaxf(v, 0.f); split2(v, hh, ll); h4.w = hh; l4.w = ll;
      *(ushort4*)(outh + o) = h4;
      *(ushort4*)(outl + o) = l4;
    }
  }
}

// ======== vq on MFMA: wave = 16 positions (one block = one 64-px row) ======
// GEMM1: z[64][16] = W[64][128] @ X[128][16] (bf16x3). LDS round-trip to
// B-layout. GEMM2: dot[64code][16] = E[64][64] @ Z[64][16] (bf16x3).
// dist = z2 + e2 - 2*dot; argmin (first-index tie-break); epilogue.
__global__ void __launch_bounds__(256) vq_mfma(
    const unsigned short* __restrict__ xh, const unsigned short* __restrict__ xl,
    const unsigned short* __restrict__ wvh, const unsigned short* __restrict__ wvl,
    const unsigned short* __restrict__ evh, const unsigned short* __restrict__ evl,
    const float* __restrict__ emb, const float* __restrict__ e2,
    const float* __restrict__ vb,
    float* __restrict__ qn, unsigned short* __restrict__ dqb,
    float* __restrict__ sum_sq, int* __restrict__ hist)
{
  __shared__ float zsh[4][16][65];
  __shared__ int lh[64];
  const int tid = threadIdx.x;
  const int wv = tid >> 6, lane = tid & 63;
  const int quad = lane >> 4, l15 = lane & 15;
  const int y = blockIdx.x;                // row 0..63
  const int b = blockIdx.z;
  const int x = wv * 16 + l15;             // lane's position x (B-operand col)
  if (tid < 64) lh[tid] = 0;

  // ---- GEMM1: z = vqc_w @ x  (bias init) ----
  f32x4 zacc[4];
  #pragma unroll
  for (int m = 0; m < 4; ++m) {
    float4 bv = *(const float4*)(vb + m * 16 + quad * 4);
    zacc[m][0] = bv.x; zacc[m][1] = bv.y; zacc[m][2] = bv.z; zacc[m][3] = bv.w;
  }
  size_t xoff = ((size_t)b * 4356 + (size_t)(y + 1) * 66 + (x + 1)) * 128;
  #pragma unroll
  for (int k0 = 0; k0 < 128; k0 += 32) {
    short8 bh = *(const short8*)(xh + xoff + k0 + quad * 8);
    short8 bl = *(const short8*)(xl + xoff + k0 + quad * 8);
    #pragma unroll
    for (int m = 0; m < 4; ++m) {
      short8 ah = *(const short8*)(wvh + (size_t)(m * 16 + l15) * 128 + k0 + quad * 8);
      short8 al = *(const short8*)(wvl + (size_t)(m * 16 + l15) * 128 + k0 + quad * 8);
      zacc[m] = __builtin_amdgcn_mfma_f32_16x16x32_bf16(ah, bh, zacc[m], 0, 0, 0);
      zacc[m] = __builtin_amdgcn_mfma_f32_16x16x32_bf16(ah, bl, zacc[m], 0, 0, 0);
      zacc[m] = __builtin_amdgcn_mfma_f32_16x16x32_bf16(al, bh, zacc[m], 0, 0, 0);
    }
  }

  // z -> LDS [pos][dim] (pad 65 to break banks); |z|^2 partial + butterfly
  float z2p = 0.f;
  #pragma unroll
  for (int m = 0; m < 4; ++m)
    #pragma unroll
    for (int r = 0; r < 4; ++r) {
      float zv = zacc[m][r];
      zsh[wv][l15][m * 16 + quad * 4 + r] = zv;
      z2p += zv * zv;
    }
  z2p += __shfl_xor(z2p, 16);
  z2p += __shfl_xor(z2p, 32);
  __syncthreads();

  // ---- GEMM2: dot = emb @ z ----
  f32x4 dacc[4];
  #pragma unroll
  for (int m = 0; m < 4; ++m) { dacc[m][0]=0.f; dacc[m][1]=0.f; dacc[m][2]=0.f; dacc[m][3]=0.f; }
  #pragma unroll
  for (int k0 = 0; k0 < 64; k0 += 32) {
    short8 bh, bl;
    #pragma unroll
    for (int j = 0; j < 8; ++j) {
      float zv = zsh[wv][l15][k0 + quad * 8 + j];
      unsigned short hh, ll;
      split2(zv, hh, ll);
      bh[j] = (short)hh; bl[j] = (short)ll;
    }
    #pragma unroll
    for (int m = 0; m < 4; ++m) {
      short8 ah = *(const short8*)(evh + (size_t)(m * 16 + l15) * 64 + k0 + quad * 8);
      short8 al = *(const short8*)(evl + (size_t)(m * 16 + l15) * 64 + k0 + quad * 8);
      dacc[m] = __builtin_amdgcn_mfma_f32_16x16x32_bf16(ah, bh, dacc[m], 0, 0, 0);
      dacc[m] = __builtin_amdgcn_mfma_f32_16x16x32_bf16(ah, bl, dacc[m], 0, 0, 0);
      dacc[m] = __builtin_amdgcn_mfma_f32_16x16x32_bf16(al, bh, dacc[m], 0, 0, 0);
    }
  }

  // ---- dist + argmin (first-min tie-break, matching jnp.argmin) ----
  float best = INFINITY;
  int bidx = 64;
  #pragma unroll
  for (int m = 0; m < 4; ++m) {
    float4 e2v = *(const float4*)(e2 + m * 16 + quad * 4);
    #pragma unroll
    for (int r = 0; r < 4; ++r) {
      float e2s = (r == 0) ? e2v.x : (r == 1) ? e2v.y : (r == 2) ? e2v.z : e2v.w;
      float d = z2p + e2s - 2.f * dacc[m][r];
      int code = m * 16 + quad * 4 + r;
      if (d < best || (d == best && code < bidx)) { best = d; bidx = code; }
    }
  }
  {
    float ob = __shfl_xor(best, 16);
    int   oi = __shfl_xor(bidx, 16);
    if (ob < best || (ob == best && oi < bidx)) { best = ob; bidx = oi; }
    ob = __shfl_xor(best, 32);
    oi = __shfl_xor(bidx, 32);
    if (ob < best || (ob == best && oi < bidx)) { best = ob; bidx = oi; }
  }

  // ---- epilogue: lane handles pos=(y,x) dims quad*16..+15 ----
  float ev[16];
  #pragma unroll
  for (int i = 0; i < 4; ++i) {
    float4 t = *(const float4*)(emb + (size_t)bidx * 64 + quad * 16 + i * 4);
    ev[i * 4] = t.x; ev[i * 4 + 1] = t.y; ev[i * 4 + 2] = t.z; ev[i * 4 + 3] = t.w;
  }
  float sq = 0.f;
  #pragma unroll
  for (int i = 0; i < 16; ++i) {
    float zv = zsh[wv][l15][quad * 16 + i];
    float df = ev[i] - zv;
    sq += df * df;
  }
  #pragma unroll
  for (int off = 1; off < 64; off <<= 1) sq += __shfl_xor(sq, off);
  if (lane == 0) atomicAdd(sum_sq, sq);
  if (quad == 0) atomicAdd(&lh[bidx], 1);

  int pos = y * 64 + x;
  float* qb = qn + (size_t)b * 262144 + (size_t)(quad * 16) * 4096 + pos;
  #pragma unroll
  for (int i = 0; i < 16; ++i) qb[(size_t)i * 4096] = ev[i];

  unsigned short* dq = dqb + ((size_t)b * 4356 + (size_t)(y + 1) * 66 + (x + 1)) * 64 + quad * 16;
  ushort8 d0, d1;
  #pragma unroll
  for (int i = 0; i < 8; ++i) { d0[i] = f2bf(ev[i]); d1[i] = f2bf(ev[i + 8]); }
  *(ushort8*)dq = d0;
  *(ushort8*)(dq + 8) = d1;

  __syncthreads();
  if (tid < 64) atomicAdd(&hist[tid], lh[tid]);
}

// ======== bf16 MFMA tap-GEMM (decoder), 4 tiles/wave; MODE1 parity=gridY ===
template<int IC, int OC, int MODE, bool HAS_BIAS, bool HAS_SKIP, bool RELU>
__global__ void __launch_bounds__(256) mfma_conv(
    const unsigned short* __restrict__ in, const unsigned short* __restrict__ wt,
    const float* __restrict__ bias, const unsigned short* __restrict__ skip,
    unsigned short* __restrict__ out, int in_ss, int out_ss)
{
  constexpr int OM = OC / 16;
  constexpr int NT = (MODE == 0) ? 9 : ((MODE == 1) ? 4 : 1);
  int ry = 0, rx = 0;
  if (MODE == 1) {
    int p = blockIdx.y;
    ry = p >> 1; rx = p & 1;
    wt  += (size_t)p * 4 * OC * IC;
    out += (size_t)p * 4356 * OC;
  }
  const int tid = threadIdx.x;
  const int wv = tid >> 6, lane = tid & 63;
  const int quad = lane >> 4, l15 = lane & 15;
  const int b = blockIdx.z;
  const int y = blockIdx.x * 4 + wv;
  int xs[4];
  #pragma unroll
  for (int j = 0; j < 4; ++j) xs[j] = j * 16 + l15;
  const unsigned short* inb = in + (size_t)b * (size_t)in_ss;

  f32x4 acc[OM][4];
  #pragma unroll
  for (int m = 0; m < OM; ++m) {
    const int oc0 = m * 16 + quad * 4;
    f32x4 ini = {0.f, 0.f, 0.f, 0.f};
    if (HAS_BIAS) {
      float4 bs = *(const float4*)(bias + oc0);
      ini[0] = bs.x; ini[1] = bs.y; ini[2] = bs.z; ini[3] = bs.w;
    }
    #pragma unroll
    for (int j = 0; j < 4; ++j) {
      f32x4 a = ini;
      if (HAS_SKIP) {
        size_t s = (size_t)b * (size_t)out_ss + ((size_t)(y + 1) * 66 + (xs[j] + 1)) * OC + oc0;
        ushort4 sv = *(const ushort4*)(skip + s);
        a[0] += bf2f(sv.x); a[1] += bf2f(sv.y); a[2] += bf2f(sv.z); a[3] += bf2f(sv.w);
      }
      acc[m][j] = a;
    }
  }

  #pragma unroll
  for (int t = 0; t < NT; ++t) {
    const int dy = (MODE == 0) ? (t / 3 - 1) : ((MODE == 1) ? (ry - (t >> 1)) : 0);
    const int dx = (MODE == 0) ? (t % 3 - 1) : ((MODE == 1) ? (rx - (t & 1)) : 0);
    const unsigned short* wr = wt + (size_t)t * OC * IC + (size_t)l15 * IC + quad * 8;
    #pragma unroll
    for (int k0 = 0; k0 < IC; k0 += 32) {
      short8 fb[4];
      #pragma unroll
      for (int j = 0; j < 4; ++j)
        fb[j] = *(const short8*)(inb + ((size_t)(y + dy + 1) * 66 + (xs[j] + dx + 1)) * IC + quad * 8 + k0);
      #pragma unroll
      for (int m = 0; m < OM; ++m) {
        short8 fa = *(const short8*)(wr + (size_t)m * 16 * IC + k0);
        #pragma unroll
        for (int j = 0; j < 4; ++j)
          acc[m][j] = __builtin_amdgcn_mfma_f32_16x16x32_bf16(fa, fb[j], acc[m][j], 0, 0, 0);
      }
    }
  }

  #pragma unroll
  for (int m = 0; m < OM; ++m) {
    const int oc0 = m * 16 + quad * 4;
    #pragma unroll
    for (int j = 0; j < 4; ++j) {
      unsigned short* o = out + (size_t)b * (size_t)out_ss
                        + ((size_t)(y + 1) * 66 + (xs[j] + 1)) * OC + oc0;
      ushort4 u4;
      float v;
      v = acc[m][j][0]; if (RELU) v = fmaxf(v, 0.f); u4.x = f2bf(v);
      v = acc[m][j][1]; if (RELU) v = fmaxf(v, 0.f); u4.y = f2bf(v);
      v = acc[m][j][2]; if (RELU) v = fmaxf(v, 0.f); u4.z = f2bf(v);
      v = acc[m][j][3]; if (RELU) v = fmaxf(v, 0.f); u4.w = f2bf(v);
      *(ushort4*)o = u4;
    }
  }
}

// ======== dec_c3: LDS-free, short8 channel-octet loads (unchanged) =========
__global__ void __launch_bounds__(256) dec3_t(
    const unsigned short* __restrict__ p4, const float* __restrict__ w,
    const float* __restrict__ bias, float* __restrict__ out)
{
  int tid = threadIdx.x;
  int yr = tid >> 7, x = tid & 127;
  int y  = blockIdx.x * 2 + yr;
  int b  = blockIdx.z;

  const int kt[2][2] = {{1, 3}, {0, 2}};
  const int dt[2][2] = {{1, 0}, {2, 1}};

  const unsigned short* base[9];
  #pragma unroll
  for (int dy = 0; dy < 3; ++dy) {
    int iy = y + dy - 1;
    int py = iy & 1, u = iy >> 1;
    #pragma unroll
    for (int dx = 0; dx < 3; ++dx) {
      int ix = x + dx - 1;
      int px = ix & 1, v = ix >> 1;
      base[dy * 3 + dx] = p4 + ((size_t)(b * 4 + py * 2 + px) * 4356
                                + (size_t)(u + 1) * 66 + (v + 1)) * 64;
    }
  }

  float acc[4] = {0.f, 0.f, 0.f, 0.f};
  for (int oct = 0; oct < 8; ++oct) {
    ushort8 s[9];
    #pragma unroll
    for (int t = 0; t < 9; ++t)
      s[t] = *(const ushort8*)(base[t] + oct * 8);

    #pragma unroll
    for (int j = 0; j < 8; ++j) {
      const float* wp = w + (size_t)(oct * 8 + j) * 16;
      float v9[9];
      #pragma unroll
      for (int t = 0; t < 9; ++t) v9[t] = bf2f(s[t][j]);
      #pragma unroll
      for (int ry = 0; ry < 2; ++ry)
        #pragma unroll
        for (int rx = 0; rx < 2; ++rx)
          #pragma unroll
          for (int a = 0; a < 2; ++a)
            #pragma unroll
            for (int c2 = 0; c2 < 2; ++c2)
              acc[ry * 2 + rx] += v9[dt[ry][a] * 3 + dt[rx][c2]]
                                * wp[kt[ry][a] * 4 + kt[rx][c2]];
    }
  }

  float b0 = bias[0];
  float* ob = out + (size_t)b * 65536;
  #pragma unroll
  for (int ry = 0; ry < 2; ++ry)
    #pragma unroll
    for (int rx = 0; rx < 2; ++rx)
      ob[(2 * y + ry) * 256 + 2 * x + rx] = tanhf(acc[ry * 2 + rx] + b0);
}

// ======== aux: multi-buffer pad-ring zero ==================================
struct RingArgs {
  unsigned short* p[5];
  int icl[5];
  int H[5];
  int planes[5];
};
__global__ void rings_k(RingArgs a)
{
  int bi = blockIdx.y;
  if ((int)blockIdx.x >= a.planes[bi]) return;
  int H = a.H[bi];
  int icl = a.icl[bi];
  int C = 1 << icl;
  unsigned short* pl = a.p[bi] + (size_t)blockIdx.x * H * H * C;
  int cells = 4 * H - 4;
  int total = cells * C;
  for (int idx = threadIdx.x; idx < total; idx += 256) {
    int cell = idx >> icl;
    int e = idx & (C - 1);
    int row, col;
    if (cell < H)             { row = 0;     col = cell; }
    else if (cell < 2 * H)    { row = H - 1; col = cell - H; }
    else if (cell < 2 * H + (H - 2)) { row = cell - 2 * H + 1; col = 0; }
    else                      { row = cell - 2 * H - (H - 2) + 1; col = H - 1; }
    pl[((size_t)row * H + col) * C + e] = 0;
  }
}

// ======== aux: repack decoder weights (unchanged) ==========================
__global__ void repack_k(const float* __restrict__ c1w, const float* __restrict__ r1w,
                         const float* __restrict__ r2w, const float* __restrict__ c2w,
                         unsigned short* __restrict__ W)
{
  int idx = blockIdx.x * 256 + threadIdx.x;
  if (idx >= 286720) return;
  float val;
  if (idx < 73728) {
    int t = idx / 8192, rem = idx & 8191;
    int oc = rem >> 6, ic = rem & 63;
    int ky = t / 3, kx = t - ky * 3;
    val = c1w[((ic * 128 + oc) * 3 + (2 - ky)) * 3 + (2 - kx)];
  } else if (idx < 147456) {
    int j = idx - 73728;
    int t = j / 8192, rem = j & 8191;
    int oc = rem >> 7, ic = rem & 127;
    int ky = t / 3, kx = t - ky * 3;
    val = r1w[((oc * 128 + ic) * 3 + ky) * 3 + kx];
  } else if (idx < 155648) {
    int j = idx - 147456;
    int oc = j >> 6, ic = j & 63;
    val = r2w[oc * 64 + ic];
  } else {
    int j = idx - 155648;
    int p = j >> 15;
    int t2 = (j >> 13) & 3;
    int oc = (j >> 7) & 63;
    int ic = j & 127;
    int ry = p >> 1, rx = p & 1;
    int aY = t2 >> 1, aX = t2 & 1;
    int ky = aY ? (3 - ry) : (1 - ry);
    int kx = aX ? (3 - rx) : (1 - rx);
    val = c2w[((ic * 64 + oc) * 4 + ky) * 4 + kx];
  }
  W[idx] = f2bf(val);
}

// ======== aux: repack encoder weights hi/lo (unchanged) ====================
__global__ void repack_enc_k(const float* __restrict__ c2w, const float* __restrict__ c3w,
                             const float* __restrict__ r1w, const float* __restrict__ r2w,
                             unsigned short* __restrict__ Wh, unsigned short* __restrict__ Wl)
{
  int idx = blockIdx.x * 256 + threadIdx.x;
  if (idx >= 360448) return;
  float val;
  if (idx < 131072) {
    int t = idx >> 13;
    int rem = idx & 8191;
    int oc = rem >> 6, ic = rem & 63;
    val = c2w[(((size_t)oc * 64 + ic) << 4) + t];
  } else if (idx < 278528) {
    int j = idx - 131072;
    int t = j / 16384;
    int rem = j & 16383;
    int oc = rem >> 7, ic = rem & 127;
    val = c3w[((size_t)oc * 128 + ic) * 9 + t];
  } else if (idx < 352256) {
    int j = idx - 278528;
    int t = j / 8192;
    int rem = j & 8191;
    int oc = rem >> 7, ic = rem & 127;
    val = r1w[((size_t)oc * 128 + ic) * 9 + t];
  } else {
    int j = idx - 352256;
    int oc = j >> 6, ic = j & 63;
    val = r2w[oc * 64 + ic];
  }
  unsigned short h = f2bf(val);
  Wh[idx] = h;
  Wl[idx] = f2bf(val - bf2f(h));
}

// ======== aux: repack vq weights (vqc_w, emb) hi/lo + e2 table =============
__global__ void repack_vq_k(const float* __restrict__ vqw, const float* __restrict__ emb,
                            unsigned short* __restrict__ wvh, unsigned short* __restrict__ wvl,
                            unsigned short* __restrict__ evh, unsigned short* __restrict__ evl,
                            float* __restrict__ e2)
{
  int idx = blockIdx.x * 256 + threadIdx.x;
  if (idx < 8192) {
    float v = vqw[idx];                  // (64,128) row-major = A[oc][ic]
    unsigned short h = f2bf(v);
    wvh[idx] = h;
    wvl[idx] = f2bf(v - bf2f(h));
  } else if (idx < 12288) {
    int j = idx - 8192;
    float v = emb[j];                    // (64,64) row-major
    unsigned short h = f2bf(v);
    evh[j] = h;
    evl[j] = f2bf(v - bf2f(h));
  }
  if (idx < 64) {
    float s = 0.f;
    for (int d = 0; d < 64; ++d) { float e = emb[idx * 64 + d]; s += e * e; }
    e2[idx] = s;
  }
}

// ======== scratch init + scalar finalize ===================================
__global__ void init_k(float* sum_sq, int* hist)
{
  int t = threadIdx.x;
  if (t == 0) sum_sq[0] = 0.f;
  if (t < 64) hist[t] = 0;
}

__global__ void finalize_k(const float* __restrict__ sum_sq, const int* __restrict__ hist,
                           float* __restrict__ loss_out, float* __restrict__ perp_out)
{
  if (threadIdx.x == 0) {
    float mse = sum_sq[0] / (float)NELEM;
    loss_out[0] = 1.25f * mse;
    float ent = 0.f;
    for (int k = 0; k < 64; ++k) {
      float p = (float)hist[k] / (float)NPOS;
      ent += p * logf(p + 1e-10f);
    }
    perp_out[0] = expf(-ent);
  }
}

// ---------------------------------------------------------------------------
extern "C" void kernel_launch(void* const* d_in, const int* in_sizes, int n_in,
                              void* d_out, int out_size, void* d_ws, size_t ws_size,
                              hipStream_t stream)
{
  const float* x        = (const float*)d_in[0];
  const float* enc_c1_w = (const float*)d_in[1];
  const float* enc_c1_b = (const float*)d_in[2];
  const float* enc_c2_w = (const float*)d_in[3];
  const float* enc_c2_b = (const float*)d_in[4];
  const float* enc_c3_w = (const float*)d_in[5];
  const float* enc_c3_b = (const float*)d_in[6];
  const float* enc_r1_w = (const float*)d_in[7];
  const float* enc_r2_w = (const float*)d_in[8];
  const float* vqc_w    = (const float*)d_in[9];
  const float* vqc_b    = (const float*)d_in[10];
  const float* emb      = (const float*)d_in[11];
  const float* dec_c1_w = (const float*)d_in[12];
  const float* dec_c1_b = (const float*)d_in[13];
  const float* dec_r1_w = (const float*)d_in[14];
  const float* dec_r2_w = (const float*)d_in[15];
  const float* dec_c2_w = (const float*)d_in[16];
  const float* dec_c2_b = (const float*)d_in[17];
  const float* dec_c3_w = (const float*)d_in[18];
  const float* dec_c3_b = (const float*)d_in[19];

  float* out      = (float*)d_out;
  float* loss_out = out;
  float* xre_out  = out + 1;
  float* perp_out = out + 1 + 2097152;
  float* qn_out   = out + 2 + 2097152;

  float* sum_sq = (float*)d_ws;
  int*   hist   = (int*)d_ws + 1;
  char*  pool   = (char*)d_ws + 1024;

  unsigned short* Wd  = (unsigned short*)(pool + 0);
  unsigned short* Weh = (unsigned short*)(pool + 600000);
  unsigned short* Wel = (unsigned short*)(pool + 1400000);
  // vq weights in the gap before E1h
  unsigned short* Wvh = (unsigned short*)(pool + 2121728);
  unsigned short* Wvl = (unsigned short*)(pool + 2138112);
  unsigned short* Evh = (unsigned short*)(pool + 2154496);
  unsigned short* Evl = (unsigned short*)(pool + 2162688);
  float*          E2  = (float*)(pool + 2170880);
  unsigned short* E1h = (unsigned short*)(pool + 2200000);
  unsigned short* E1l = (unsigned short*)(pool + 71500000);
  unsigned short* B2h = (unsigned short*)(pool + 141000000);
  unsigned short* B2l = (unsigned short*)(pool + 177000000);
  unsigned short* R0h = (unsigned short*)(pool + 2200000);
  unsigned short* R0l = (unsigned short*)(pool + 38000000);
  unsigned short* Hh  = (unsigned short*)(pool + 74000000);
  unsigned short* Hl  = (unsigned short*)(pool + 92000000);
  unsigned short* X1h = (unsigned short*)(pool + 141000000);
  unsigned short* X1l = (unsigned short*)(pool + 177000000);
  unsigned short* X2h = (unsigned short*)(pool + 2200000);
  unsigned short* X2l = (unsigned short*)(pool + 38000000);
  unsigned short* Dq  = (unsigned short*)(pool + 213000000);
  unsigned short* Y1  = (unsigned short*)(pool + 141000000);
  unsigned short* S   = (unsigned short*)(pool + 110000000);
  unsigned short* Y2  = (unsigned short*)(pool + 177000000);
  unsigned short* P4  = (unsigned short*)(pool + 2200000);

  const int SS64  = 278784;
  const int SS128 = 557568;
  const int SSP4  = 1115136;

  hipLaunchKernelGGL(init_k, dim3(1), dim3(128), 0, stream, sum_sq, hist);
  hipLaunchKernelGGL(repack_k, dim3(1120), dim3(256), 0, stream,
                     dec_c1_w, dec_r1_w, dec_r2_w, dec_c2_w, Wd);
  hipLaunchKernelGGL(repack_enc_k, dim3(1408), dim3(256), 0, stream,
                     enc_c2_w, enc_c3_w, enc_r1_w, enc_r2_w, Weh, Wel);
  hipLaunchKernelGGL(repack_vq_k, dim3(48), dim3(256), 0, stream,
                     vqc_w, emb, Wvh, Wvl, Evh, Evl, E2);

  // rings group 1: fresh regions
  {
    RingArgs a;
    a.p[0] = E1h; a.icl[0] = 6; a.H[0] = 130; a.planes[0] = 32;
    a.p[1] = E1l; a.icl[1] = 6; a.H[1] = 130; a.planes[1] = 32;
    a.p[2] = B2h; a.icl[2] = 7; a.H[2] = 66;  a.planes[2] = 32;
    a.p[3] = B2l; a.icl[3] = 7; a.H[3] = 66;  a.planes[3] = 32;
    a.p[4] = Dq;  a.icl[4] = 6; a.H[4] = 66;  a.planes[4] = 32;
    hipLaunchKernelGGL(rings_k, dim3(32, 5), dim3(256), 0, stream, a);
  }

  // ---- encoder ----
  hipLaunchKernelGGL(enc1_t, dim3(64, 4, 32), dim3(256), 0, stream,
                     x, enc_c1_w, enc_c1_b, E1h, E1l);
  hipLaunchKernelGGL((mfma_enc<64, 128, 1, true, true>),
                     dim3(16, 1, 32), dim3(256), 0, stream,
                     E1h, E1l, Weh, Wel, enc_c2_b, nullptr, nullptr, B2h, B2l);

  // rings group 2
  {
    RingArgs a;
    a.p[0] = R0h; a.icl[0] = 7; a.H[0] = 66; a.planes[0] = 32;
    a.p[1] = R0l; a.icl[1] = 7; a.H[1] = 66; a.planes[1] = 32;
    a.p[2] = Hh;  a.icl[2] = 6; a.H[2] = 66; a.planes[2] = 32;
    a.p[3] = Hl;  a.icl[3] = 6; a.H[3] = 66; a.planes[3] = 32;
    a.p[4] = S;   a.icl[4] = 6; a.H[4] = 66; a.planes[4] = 32;
    hipLaunchKernelGGL(rings_k, dim3(32, 5), dim3(256), 0, stream, a);
  }

  hipLaunchKernelGGL((mfma_enc<128, 128, 0, true, true>),
                     dim3(16, 1, 32), dim3(256), 0, stream,
                     B2h, B2l, Weh + 131072, Wel + 131072, enc_c3_b,
                     nullptr, nullptr, R0h, R0l);

  // rings group 3
  {
    RingArgs a;
    a.p[0] = X1h; a.icl[0] = 7; a.H[0] = 66; a.planes[0] = 32;
    a.p[1] = X1l; a.icl[1] = 7; a.H[1] = 66; a.planes[1] = 32;
    a.p[2] = nullptr; a.icl[2] = 0; a.H[2] = 2; a.planes[2] = 0;
    a.p[3] = nullptr; a.icl[3] = 0; a.H[3] = 2; a.planes[3] = 0;
    a.p[4] = nullptr; a.icl[4] = 0; a.H[4] = 2; a.planes[4] = 0;
    hipLaunchKernelGGL(rings_k, dim3(32, 2), dim3(256), 0, stream, a);
  }

  hipLaunchKernelGGL((mfma_enc<128, 64, 0, false, true>),
                     dim3(16, 1, 32), dim3(256), 0, stream,
                     R0h, R0l, Weh + 278528, Wel + 278528, nullptr,
                     nullptr, nullptr, Hh, Hl);
  hipLaunchKernelGGL((mfma_enc<64, 128, 2, false, true>),
                     dim3(16, 1, 32), dim3(256), 0, stream,
                     Hh, Hl, Weh + 352256, Wel + 352256, nullptr,
                     R0h, R0l, X1h, X1l);

  // rings group 4
  {
    RingArgs a;
    a.p[0] = X2h; a.icl[0] = 7; a.H[0] = 66; a.planes[0] = 32;
    a.p[1] = X2l; a.icl[1] = 7; a.H[1] = 66; a.planes[1] = 32;
    a.p[2] = nullptr; a.icl[2] = 0; a.H[2] = 2; a.planes[2] = 0;
    a.p[3] = nullptr; a.icl[3] = 0; a.H[3] = 2; a.planes[3] = 0;
    a.p[4] = nullptr; a.icl[4] = 0; a.H[4] = 2; a.planes[4] = 0;
    hipLaunchKernelGGL(rings_k, dim3(32, 2), dim3(256), 0, stream, a);
  }

  hipLaunchKernelGGL((mfma_enc<128, 64, 0, false, true>),
                     dim3(16, 1, 32), dim3(256), 0, stream,
                     X1h, X1l, Weh + 278528, Wel + 278528, nullptr,
                     nullptr, nullptr, Hh, Hl);
  hipLaunchKernelGGL((mfma_enc<64, 128, 2, false, true>),
                     dim3(16, 1, 32), dim3(256), 0, stream,
                     Hh, Hl, Weh + 352256, Wel + 352256, nullptr,
                     X1h, X1l, X2h, X2l);

  // ---- VQ on MFMA ----
  hipLaunchKernelGGL(vq_mfma, dim3(64, 1, 32), dim3(256), 0, stream,
                     X2h, X2l, Wvh, Wvl, Evh, Evl, emb, E2, vqc_b,
                     qn_out, Dq, sum_sq, hist);

  // rings group 5: decoder regions
  {
    RingArgs a;
    a.p[0] = Y1;  a.icl[0] = 7; a.H[0] = 66; a.planes[0] = 32;
    a.p[1] = Y2;  a.icl[1] = 7; a.H[1] = 66; a.planes[1] = 32;
    a.p[2] = P4;  a.icl[2] = 6; a.H[2] = 66; a.planes[2] = 128;
    a.p[3] = nullptr; a.icl[3] = 0; a.H[3] = 2; a.planes[3] = 0;
    a.p[4] = nullptr; a.icl[4] = 0; a.H[4] = 2; a.planes[4] = 0;
    hipLaunchKernelGGL(rings_k, dim3(128, 3), dim3(256), 0, stream, a);
  }

  // ---- decoder (bf16 MFMA) ----
  hipLaunchKernelGGL((mfma_conv<64, 128, 0, true, false, true>),
                     dim3(16, 1, 32), dim3(256), 0, stream,
                     Dq, Wd, dec_c1_b, nullptr, Y1, SS64, SS128);
  hipLaunchKernelGGL((mfma_conv<128, 64, 0, false, false, true>),
                     dim3(16, 1, 32), dim3(256), 0, stream,
                     Y1, Wd + 73728, nullptr, nullptr, S, SS128, SS64);
  hipLaunchKernelGGL((mfma_conv<64, 128, 2, false, true, true>),
                     dim3(16, 1, 32), dim3(256), 0, stream,
                     S, Wd + 147456, nullptr, Y1, Y2, SS64, SS128);
  hipLaunchKernelGGL((mfma_conv<128, 64, 0, false, false, true>),
                     dim3(16, 1, 32), dim3(256), 0, stream,
                     Y2, Wd + 73728, nullptr, nullptr, S, SS128, SS64);
  hipLaunchKernelGGL((mfma_conv<64, 128, 2, false, true, true>),
                     dim3(16, 1, 32), dim3(256), 0, stream,
                     S, Wd + 147456, nullptr, Y2, Y1, SS64, SS128);

  // dec_c2: all 4 parities in one launch (grid.y = parity)
  hipLaunchKernelGGL((mfma_conv<128, 64, 1, true, false, true>),
                     dim3(16, 4, 32), dim3(256), 0, stream,
                     Y1, Wd + 155648, dec_c2_b, nullptr, P4, SS128, SSP4);

  hipLaunchKernelGGL(dec3_t, dim3(64, 1, 32), dim3(256), 0, stream,
                     P4, dec_c3_w, dec_c3_b, xre_out);

  hipLaunchKernelGGL(finalize_k, dim3(1), dim3(64), 0, stream,
                     sum_sq, hist, loss_out, perp_out);
}